// Round 10
// baseline (659.349 us; speedup 1.0000x reference)
//
#include <hip/hip_runtime.h>
#include <math.h>

typedef _Float16 half_t;
typedef __attribute__((ext_vector_type(4))) _Float16 half4;
typedef __attribute__((ext_vector_type(8))) _Float16 half8;
typedef __attribute__((ext_vector_type(4))) float f32x4;

__device__ __forceinline__ f32x4 MFMA16(half4 a, half4 b, f32x4 c) {
  return __builtin_amdgcn_mfma_f32_16x16x16f16(a, b, c, 0, 0, 0);
}
__device__ __forceinline__ f32x4 MFMA32(half8 a, half8 b, f32x4 c) {
  return __builtin_amdgcn_mfma_f32_16x16x32_f16(a, b, c, 0, 0, 0);
}

#if __has_builtin(__builtin_amdgcn_exp2f)
#define EXP2F(x) __builtin_amdgcn_exp2f(x)
#else
#define EXP2F(x) exp2f(x)
#endif

// XOR swizzle for 64-float f32 rows (quad ^= row&15) — k_slots only
__device__ __forceinline__ int SWi(int row, int col) {
  return (row << 6) | (((((col >> 2) ^ row) & 15)) << 2) | (col & 3);
}
__device__ __forceinline__ int SW4i(int row, int q) {
  return (row << 6) | ((((q ^ row) & 15)) << 2);
}
// f16 rows of 64 cols, 16B units: unit8 ^= row&7
__device__ __forceinline__ int XH8W(int t, int k0) {
  return (t << 6) | ((((k0 >> 3) ^ t) & 7) << 3) | (k0 & 7);
}
__device__ __forceinline__ int XH8R(int t, int u8) {
  return (t << 6) | (((u8 ^ t) & 7) << 3);
}
// f16 rows of 32 cols (FFN hidden), 16B units: unit ^= row&3
__device__ __forceinline__ int HB8W(int t, int h) {
  return (t << 5) | ((((h >> 3) ^ t) & 3) << 3) | (h & 7);
}
__device__ __forceinline__ int HB8R(int t, int u8) {
  return (t << 5) | (((u8 ^ t) & 3) << 3);
}

// fast exact-gelu via Abramowitz-Stegun 7.1.26 erf (|err| <= 1.5e-7)
__device__ __forceinline__ float fast_gelu(float v) {
  float x = 0.70710678118654752f * v;
  float ax = fabsf(x);
  float t = 1.0f / fmaf(0.3275911f, ax, 1.0f);
  float poly = t * fmaf(t, fmaf(t, fmaf(t, fmaf(t, 1.061405429f, -1.453152027f),
                                        1.421413741f), -0.284496736f), 0.254829592f);
  float e = EXP2F(-1.4426950408889634f * ax * ax);
  float erfax = fmaf(-poly, e, 1.0f);
  float er = __builtin_copysignf(erfax, x);
  return 0.5f * v * (1.0f + er);
}

// ---------------------------------------------------------------------------
// prepack: weights -> f16 MFMA fragment order (unchanged).
// h8 units (1024B): lane ln holds row tile*16+(ln&15), k = ks2*32+(ln>>4)*8+j.
//   WQ8[0,24) W18[24,56) W28[56,88) Wc8[88,118)
// h4 units (512B) at half-offset 60416: WO4 16 units, Pw4 40 units.
// ---------------------------------------------------------------------------
__global__ void k_prepack(const float* __restrict__ conv_w,
                          const float* __restrict__ proj_w,
                          const float* __restrict__ Wqkv,
                          const float* __restrict__ Wo,
                          const float* __restrict__ W1,
                          const float* __restrict__ W2,
                          half_t* __restrict__ dst) {
  int id = blockIdx.x * 512 + threadIdx.x;
  if (id < 7552) {
    int unit = id >> 6, ln = id & 63;
    int li = ln & 15, g8 = (ln >> 4) * 8;
    float v[8];
    if (unit < 24) {                     // Wqkv [192][64]
      int rt = unit >> 1, ks2 = unit & 1;
      const float* s = &Wqkv[(rt * 16 + li) * 64 + ks2 * 32 + g8];
#pragma unroll
      for (int r = 0; r < 8; ++r) v[r] = s[r];
    } else if (unit < 56) {              // W1 [256][64]
      int u = unit - 24, rt = u >> 1, ks2 = u & 1;
      const float* s = &W1[(rt * 16 + li) * 64 + ks2 * 32 + g8];
#pragma unroll
      for (int r = 0; r < 8; ++r) v[r] = s[r];
    } else if (unit < 88) {              // W2 [64][256]
      int u = unit - 56, ct = u >> 3, ks2 = u & 7;
      const float* s = &W2[(ct * 16 + li) * 256 + ks2 * 32 + g8];
#pragma unroll
      for (int r = 0; r < 8; ++r) v[r] = s[r];
    } else {                             // conv_w [150][81] pad [160][96]
      int u = unit - 88, ct = u / 3, ks2 = u - ct * 3;
      int row = ct * 16 + li;
#pragma unroll
      for (int r = 0; r < 8; ++r) {
        int col = ks2 * 32 + g8 + r;
        v[r] = (row < 150 && col < 81) ? conv_w[row * 81 + col] : 0.f;
      }
    }
    half8 o;
#pragma unroll
    for (int r = 0; r < 8; ++r) o[r] = (half_t)v[r];
    ((half8*)dst)[id] = o;
  } else if (id < 11136) {
    int id2 = id - 7552;
    int unit = id2 >> 6, ln = id2 & 63;
    int li = ln & 15, gq = (ln >> 4) * 4;
    float v[4];
    if (unit < 16) {                     // Wo [64][64], K=16 frags
      int ct = unit >> 2, h = unit & 3;
      const float* s = &Wo[(ct * 16 + li) * 64 + h * 16 + gq];
#pragma unroll
      for (int r = 0; r < 4; ++r) v[r] = s[r];
    } else {                             // proj_w [64][150] pad [64][160]
      int u = unit - 16, dt = u / 10, ct = u - dt * 10;
#pragma unroll
      for (int r = 0; r < 4; ++r) {
        int col = ct * 16 + gq + r;
        v[r] = (col < 150) ? proj_w[(dt * 16 + li) * 150 + col] : 0.f;
      }
    }
    half4 o;
#pragma unroll
    for (int r = 0; r < 4; ++r) o[r] = (half_t)v[r];
    ((half4*)(dst + 60416))[id2] = o;
  }
}

// ---------------------------------------------------------------------------
// k_net v4: conv -> LN1 -> attn (4 single-head passes) -> LN2 -> FFN (8x32)
// -> tln. Residual in registers; 48,128B LDS -> 3 blocks/CU (75% occupancy).
// VGPR must stay <= 64 (8-wave tier); R9 measured 60 with this pressure.
// launch_bounds(512,6): 6 waves/EU = 3 blocks/CU for 512-thread blocks.
// LDS (bytes): Xh@0 (26,624; xsh 2,520 + OS 34,816 alias)
//   attn: Kb@26,624 (8,320 [208][20])  VT@34,944 (6,784 [16][212])
//   ffn:  W1S@26,624 (4,096) W2S@30,720 (4,096) Hb@34,816 (13,312 [208][32])
// ---------------------------------------------------------------------------
__global__ __launch_bounds__(512, 6) void k_net(
    const float* __restrict__ x,
    const half8* __restrict__ WQ8, const half8* __restrict__ W18,
    const half8* __restrict__ W28, const half8* __restrict__ Wc8,
    const half4* __restrict__ WO4, const half4* __restrict__ Pw4,
    const float* __restrict__ proj_b,
    const float* __restrict__ ln1_g, const float* __restrict__ ln1_b,
    const float* __restrict__ bqkv, const float* __restrict__ bo,
    const float* __restrict__ ln2_g, const float* __restrict__ ln2_b,
    const float* __restrict__ b1, const float* __restrict__ b2,
    const float* __restrict__ tln_g, const float* __restrict__ tln_b,
    float* __restrict__ tokens) {
  extern __shared__ __align__(16) char pool[];
  half_t* xsh = (half_t*)pool;                 // conv phase alias
  half_t* Xh = (half_t*)pool;                  // LN1..FFN [208][64]
  half_t* Kb = (half_t*)(pool + 26624);        // attn: [208][20]
  half_t* VT = (half_t*)(pool + 34944);        // attn: [16][212]
  half8* W1S = (half8*)(pool + 26624);         // ffn alias, 4 units
  half8* W2S = (half8*)(pool + 30720);         // ffn alias, 4 units
  half_t* Hb = (half_t*)(pool + 34816);        // ffn alias [208][32]
  float* OS = (float*)pool;                    // out alias, 8x16x68 f32

  const int b = blockIdx.x, tid = threadIdx.x;
  const int wv = tid >> 6, ln = tid & 63, g = ln >> 4, li = ln & 15;
  const size_t base = (size_t)b * 12544;

  f32x4 res[2][4];
#pragma unroll
  for (int qi = 0; qi < 2; ++qi)
#pragma unroll
    for (int ct = 0; ct < 4; ++ct) res[qi][ct] = f32x4{0.f, 0.f, 0.f, 0.f};

  // ---- conv phase: stage image as f16 ----
  for (int i = tid; i < 1260; i += 512) xsh[i] = (half_t)0.f;
  __syncthreads();
  for (int i = tid; i < 784; i += 512) {
    int r = i / 28, c = i - r * 28;
    xsh[(r + 4) * 36 + c + 4] = (half_t)x[b * 784 + i];
  }
  __syncthreads();

#pragma unroll
  for (int qi = 0; qi < 2; ++qi) {
    int qt = wv + 8 * qi;
    if (qt < 13) {
      int pp = qt * 16 + li;
      int pc = (pp < 196) ? pp : 195;
      int oy = pc / 14, ox = pc - oy * 14;
      int pbase = oy * 72 + ox * 2;
      half8 bf[3];
#pragma unroll
      for (int ks2 = 0; ks2 < 3; ++ks2) {
#pragma unroll
        for (int j = 0; j < 8; ++j) {
          int tap = ks2 * 32 + g * 8 + j;   // 0..95, valid <= 80
          half_t v = (half_t)0.f;
          if (tap <= 80) {
            int ky = tap / 9;
            v = xsh[pbase + ky * 27 + tap];
          }
          bf[ks2][j] = v;
        }
      }
      // ct-outer / dt-inner: only ONE hf fragment live (register pressure)
#pragma unroll
      for (int ct = 0; ct < 10; ++ct) {
        f32x4 acc = {0.f, 0.f, 0.f, 0.f};
#pragma unroll
        for (int ks2 = 0; ks2 < 3; ++ks2)
          acc = MFMA32(Wc8[(ct * 3 + ks2) * 64 + ln], bf[ks2], acc);
        half4 hf;
#pragma unroll
        for (int r = 0; r < 4; ++r) hf[r] = (half_t)fast_gelu(acc[r]);
#pragma unroll
        for (int dt = 0; dt < 4; ++dt)
          res[qi][dt] = MFMA16(Pw4[(dt * 10 + ct) * 64 + ln], hf, res[qi][dt]);
      }
#pragma unroll
      for (int dt = 0; dt < 4; ++dt) {
        float4 pb4 = *(const float4*)&proj_b[dt * 16 + g * 4];
        res[qi][dt][0] += pb4.x; res[qi][dt][1] += pb4.y;
        res[qi][dt][2] += pb4.z; res[qi][dt][3] += pb4.w;
      }
    }
  }
  __syncthreads();   // xsh done; Xh region free

  // ---- LN1 (in-register) -> Xh ----
  for (int i = tid; i < 768; i += 512)
    Xh[(196 + (i >> 6)) * 64 + (i & 63)] = (half_t)0.f;
#pragma unroll
  for (int qi = 0; qi < 2; ++qi) {
    int qt = wv + 8 * qi;
    if (qt < 13) {
      float sum = 0.f;
#pragma unroll
      for (int ct = 0; ct < 4; ++ct)
#pragma unroll
        for (int r = 0; r < 4; ++r) sum += res[qi][ct][r];
      sum += __shfl_xor(sum, 16, 64);
      sum += __shfl_xor(sum, 32, 64);
      float mu = sum * 0.015625f;
      float vs = 0.f;
#pragma unroll
      for (int ct = 0; ct < 4; ++ct)
#pragma unroll
        for (int r = 0; r < 4; ++r) { float d = res[qi][ct][r] - mu; vs += d * d; }
      vs += __shfl_xor(vs, 16, 64);
      vs += __shfl_xor(vs, 32, 64);
      float rs = rsqrtf(vs * 0.015625f + 1e-5f);
      int t = qt * 16 + li;
      if (t < 196) {
#pragma unroll
        for (int ct = 0; ct < 4; ++ct) {
          int k0 = ct * 16 + g * 4;
          float4 gg = *(const float4*)&ln1_g[k0];
          float4 bb = *(const float4*)&ln1_b[k0];
          half4 o;
          o[0] = (half_t)((res[qi][ct][0] - mu) * rs * gg.x + bb.x);
          o[1] = (half_t)((res[qi][ct][1] - mu) * rs * gg.y + bb.y);
          o[2] = (half_t)((res[qi][ct][2] - mu) * rs * gg.z + bb.z);
          o[3] = (half_t)((res[qi][ct][3] - mu) * rs * gg.w + bb.w);
          *(half4*)&Xh[XH8W(t, k0)] = o;
        }
      }
    }
  }
  __syncthreads();

  // ---- Q fragments for all 4 heads (scale folds 1/4*log2e) ----
  half4 qf[2][4];
#pragma unroll
  for (int qi = 0; qi < 2; ++qi) {
    int qt = wv + 8 * qi;
    if (qt < 13) {
#pragma unroll
      for (int h = 0; h < 4; ++h) {
        f32x4 acc = {0.f, 0.f, 0.f, 0.f};
#pragma unroll
        for (int ks2 = 0; ks2 < 2; ++ks2)
          acc = MFMA32(WQ8[(h * 2 + ks2) * 64 + ln],
                       *(const half8*)&Xh[XH8R(qt * 16 + li, ks2 * 4 + g)], acc);
#pragma unroll
        for (int r = 0; r < 4; ++r)
          qf[qi][h][r] = (half_t)((acc[r] + bqkv[h * 16 + g * 4 + r]) *
                                  0.36067376022224085f);
      }
    }
  }

  // ---- attention: 4 single-head passes ----
  for (int h = 0; h < 4; ++h) {
    if (wv < 4) {   // K staging (waves 0-3)
      half8 af[2];
#pragma unroll
      for (int ks2 = 0; ks2 < 2; ++ks2)
        af[ks2] = WQ8[((4 + h) * 2 + ks2) * 64 + ln];
      float bias[4];
#pragma unroll
      for (int r = 0; r < 4; ++r) bias[r] = bqkv[64 + h * 16 + g * 4 + r];
      for (int tt = wv; tt < 13; tt += 4) {
        int trow = tt * 16 + li;
        f32x4 acc = {0.f, 0.f, 0.f, 0.f};
#pragma unroll
        for (int ks2 = 0; ks2 < 2; ++ks2)
          acc = MFMA32(af[ks2], *(const half8*)&Xh[XH8R(trow, ks2 * 4 + g)], acc);
#pragma unroll
        for (int r = 0; r < 4; ++r)
          Kb[trow * 20 + g * 4 + r] = (half_t)(acc[r] + bias[r]);
      }
    } else {        // V^T staging (waves 4-7)
      half8 af[2];
#pragma unroll
      for (int ks2 = 0; ks2 < 2; ++ks2)
        af[ks2] = WQ8[((8 + h) * 2 + ks2) * 64 + ln];
      float bias[4];
#pragma unroll
      for (int r = 0; r < 4; ++r) bias[r] = bqkv[128 + h * 16 + g * 4 + r];
      for (int tt = wv - 4; tt < 13; tt += 4) {
        int trow = tt * 16 + li;
        f32x4 acc = {0.f, 0.f, 0.f, 0.f};
#pragma unroll
        for (int ks2 = 0; ks2 < 2; ++ks2)
          acc = MFMA32(af[ks2], *(const half8*)&Xh[XH8R(trow, ks2 * 4 + g)], acc);
#pragma unroll
        for (int r = 0; r < 4; ++r)
          VT[(g * 4 + r) * 212 + trow] = (half_t)(acc[r] + bias[r]);
      }
    }
    __syncthreads();
    // streamed QK^T -> exp2 (no max-subtract; scores bounded) -> PV -> Wo
#pragma unroll
    for (int qi = 0; qi < 2; ++qi) {
      int qt = wv + 8 * qi;
      if (qt < 13) {
        float es = 0.f;
        f32x4 oa = {0.f, 0.f, 0.f, 0.f};
#pragma unroll
        for (int nt = 0; nt < 13; ++nt) {
          f32x4 zz = {0.f, 0.f, 0.f, 0.f};
          f32x4 sv = MFMA16(*(const half4*)&Kb[(nt * 16 + li) * 20 + g * 4],
                            qf[qi][h], zz);
          if (nt == 12 && g > 0) { sv[0] = -3e38f; sv[1] = -3e38f; sv[2] = -3e38f; sv[3] = -3e38f; }
          half4 pf;
#pragma unroll
          for (int r = 0; r < 4; ++r) {
            float e = EXP2F(sv[r]);
            es += e;
            pf[r] = (half_t)e;
          }
          oa = MFMA16(*(const half4*)&VT[li * 212 + nt * 16 + g * 4], pf, oa);
        }
        es += __shfl_xor(es, 16, 64);
        es += __shfl_xor(es, 32, 64);
        float inv = 1.0f / es;
        half4 of;
#pragma unroll
        for (int r = 0; r < 4; ++r) of[r] = (half_t)(oa[r] * inv);
#pragma unroll
        for (int ct = 0; ct < 4; ++ct)
          res[qi][ct] = MFMA16(WO4[(ct * 4 + h) * 64 + ln], of, res[qi][ct]);
      }
    }
    __syncthreads();
  }
  // + bo
#pragma unroll
  for (int qi = 0; qi < 2; ++qi) {
    int qt = wv + 8 * qi;
    if (qt < 13) {
#pragma unroll
      for (int ct = 0; ct < 4; ++ct) {
        float4 bb = *(const float4*)&bo[ct * 16 + g * 4];
        res[qi][ct][0] += bb.x; res[qi][ct][1] += bb.y;
        res[qi][ct][2] += bb.z; res[qi][ct][3] += bb.w;
      }
    }
  }

  // ---- LN2 -> Xh ----
#pragma unroll
  for (int qi = 0; qi < 2; ++qi) {
    int qt = wv + 8 * qi;
    if (qt < 13) {
      float sum = 0.f;
#pragma unroll
      for (int ct = 0; ct < 4; ++ct)
#pragma unroll
        for (int r = 0; r < 4; ++r) sum += res[qi][ct][r];
      sum += __shfl_xor(sum, 16, 64);
      sum += __shfl_xor(sum, 32, 64);
      float mu = sum * 0.015625f;
      float vs = 0.f;
#pragma unroll
      for (int ct = 0; ct < 4; ++ct)
#pragma unroll
        for (int r = 0; r < 4; ++r) { float d = res[qi][ct][r] - mu; vs += d * d; }
      vs += __shfl_xor(vs, 16, 64);
      vs += __shfl_xor(vs, 32, 64);
      float rs = rsqrtf(vs * 0.015625f + 1e-5f);
      int t = qt * 16 + li;
      if (t < 196) {
#pragma unroll
        for (int ct = 0; ct < 4; ++ct) {
          int k0 = ct * 16 + g * 4;
          float4 gg = *(const float4*)&ln2_g[k0];
          float4 bb = *(const float4*)&ln2_b[k0];
          half4 o;
          o[0] = (half_t)((res[qi][ct][0] - mu) * rs * gg.x + bb.x);
          o[1] = (half_t)((res[qi][ct][1] - mu) * rs * gg.y + bb.y);
          o[2] = (half_t)((res[qi][ct][2] - mu) * rs * gg.z + bb.z);
          o[3] = (half_t)((res[qi][ct][3] - mu) * rs * gg.w + bb.w);
          *(half4*)&Xh[XH8W(t, k0)] = o;
        }
      }
    }
  }
  __syncthreads();

  // ---- FFN: 8 chunks of 32 hidden ----
  for (int ch = 0; ch < 8; ++ch) {
    if (tid < 256) {
      int u = tid >> 6, l2 = tid & 63;       // u = lnt*2+ks2
      int lnt = u >> 1, ks2 = u & 1;
      W1S[u * 64 + l2] = W18[((ch * 2 + lnt) * 2 + ks2) * 64 + l2];
    } else {
      int i2 = tid - 256;
      int ct = i2 >> 6, l2 = i2 & 63;
      W2S[ct * 64 + l2] = W28[(ct * 8 + ch) * 64 + l2];
    }
    __syncthreads();
    // H = gelu(t2 @ W1^T + b1): 26 units (13 mt x 2 lnt)
    for (int u = wv; u < 26; u += 8) {
      int mt = u >> 1, lnt = u & 1;
      f32x4 acc = {0.f, 0.f, 0.f, 0.f};
#pragma unroll
      for (int ks2 = 0; ks2 < 2; ++ks2)
        acc = MFMA32(*(const half8*)&Xh[XH8R(mt * 16 + li, ks2 * 4 + g)],
                     W1S[(lnt * 2 + ks2) * 64 + ln], acc);
      float bb = b1[ch * 32 + lnt * 16 + li];
#pragma unroll
      for (int r = 0; r < 4; ++r)
        Hb[HB8W(mt * 16 + g * 4 + r, lnt * 16 + li)] = (half_t)fast_gelu(acc[r] + bb);
    }
    __syncthreads();
    // res += W2 @ H  (K=32 over the chunk's hidden dims)
#pragma unroll
    for (int qi = 0; qi < 2; ++qi) {
      int qt = wv + 8 * qi;
      if (qt < 13) {
#pragma unroll
        for (int ct = 0; ct < 4; ++ct)
          res[qi][ct] = MFMA32(W2S[ct * 64 + ln],
                               *(const half8*)&Hb[HB8R(qt * 16 + li, g)],
                               res[qi][ct]);
      }
    }
    __syncthreads();
  }
  // + b2
#pragma unroll
  for (int qi = 0; qi < 2; ++qi) {
    int qt = wv + 8 * qi;
    if (qt < 13) {
#pragma unroll
      for (int ct = 0; ct < 4; ++ct) {
        float4 bb = *(const float4*)&b2[ct * 16 + g * 4];
        res[qi][ct][0] += bb.x; res[qi][ct][1] += bb.y;
        res[qi][ct][2] += bb.z; res[qi][ct][3] += bb.w;
      }
    }
  }

  // ---- final LN -> per-wave OS staging -> coalesced store (no barrier) ----
#pragma unroll
  for (int qi = 0; qi < 2; ++qi) {
    int qt = wv + 8 * qi;
    if (qt < 13) {
      float sum = 0.f;
#pragma unroll
      for (int ct = 0; ct < 4; ++ct)
#pragma unroll
        for (int r = 0; r < 4; ++r) sum += res[qi][ct][r];
      sum += __shfl_xor(sum, 16, 64);
      sum += __shfl_xor(sum, 32, 64);
      float mu = sum * 0.015625f;
      float vs = 0.f;
#pragma unroll
      for (int ct = 0; ct < 4; ++ct)
#pragma unroll
        for (int r = 0; r < 4; ++r) { float d = res[qi][ct][r] - mu; vs += d * d; }
      vs += __shfl_xor(vs, 16, 64);
      vs += __shfl_xor(vs, 32, 64);
      float rs = rsqrtf(vs * 0.015625f + 1e-5f);
#pragma unroll
      for (int ct = 0; ct < 4; ++ct) {
        float4 gg = *(const float4*)&tln_g[ct * 16 + g * 4];
        float4 bb = *(const float4*)&tln_b[ct * 16 + g * 4];
        float4 o;
        o.x = (res[qi][ct][0] - mu) * rs * gg.x + bb.x;
        o.y = (res[qi][ct][1] - mu) * rs * gg.y + bb.y;
        o.z = (res[qi][ct][2] - mu) * rs * gg.z + bb.z;
        o.w = (res[qi][ct][3] - mu) * rs * gg.w + bb.w;
        *(float4*)&OS[wv * 1088 + li * 68 + ct * 16 + g * 4] = o;
      }
#pragma unroll
      for (int rep = 0; rep < 4; ++rep) {
        int r4 = rep * 64 + ln;
        int row = r4 >> 4, q = r4 & 15;
        int pp = qt * 16 + row;
        if (pp < 196)
          *(float4*)&tokens[base + (size_t)pp * 64 + q * 4] =
              *(const float4*)&OS[wv * 1088 + row * 68 + q * 4];
      }
    }
  }
}

// ---------------------------------------------------------------------------
// slots: plain load (tln applied) + slot attention + spmask + classifier (f32)
// ---------------------------------------------------------------------------
__global__ __launch_bounds__(256) void k_slots(
    const float* __restrict__ tokens, const float* __restrict__ slot_q,
    const float* __restrict__ cls_w, const float* __restrict__ cls_b,
    const int* __restrict__ use_spmask_p, const int* __restrict__ grid_p,
    float* __restrict__ out) {
  __shared__ float TOK[12544];
  __shared__ float Abuf[12 * 196];
  __shared__ float SQS[12 * 64];
  __shared__ float INV[196];
  __shared__ float VV[64];
  __shared__ float Pv[12];
  __shared__ float M2[12];
  __shared__ float ISN[12];
  __shared__ float ZS[2];

  const int b = blockIdx.x, tid = threadIdx.x;
  const size_t base = (size_t)b * 12544;
  (void)grid_p;

  for (int i = tid; i < 12544; i += 256) {
    int t = i >> 6, c = i & 63;
    TOK[SWi(t, c)] = tokens[base + i];
  }
  __syncthreads();
  if (tid < 196) {
    float ss = 0.f;
#pragma unroll
    for (int q = 0; q < 16; ++q) {
      float4 v = *(const float4*)&TOK[SW4i(tid, q)];
      ss += v.x * v.x + v.y * v.y + v.z * v.z + v.w * v.w;
    }
    INV[tid] = 1.0f / fmaxf(sqrtf(ss), 1e-12f);
  }
  if (tid < 192) {
    int m = tid >> 4, l = tid & 15;
    float ss = 0.f;
#pragma unroll
    for (int c = l; c < 64; c += 16) {
      float v = slot_q[m * 64 + c];
      ss += v * v;
    }
#pragma unroll
    for (int mm = 8; mm; mm >>= 1) ss += __shfl_xor(ss, mm, 64);
    float invq = 1.0f / fmaxf(sqrtf(ss), 1e-12f);
#pragma unroll
    for (int c = l; c < 64; c += 16) SQS[m * 64 + c] = slot_q[m * 64 + c] * invq;
  }
  __syncthreads();
  for (int i = tid; i < 2352; i += 256) {
    int m = i / 196, n = i - m * 196;
    float d = 0.f;
#pragma unroll
    for (int q = 0; q < 16; ++q) {
      float4 tv = *(const float4*)&TOK[SW4i(n, q)];
      float4 sv = *(const float4*)&SQS[m * 64 + q * 4];
      d += tv.x * sv.x + tv.y * sv.y + tv.z * sv.z + tv.w * sv.w;
    }
    Abuf[i] = d * INV[n] * 0.125f;
  }
  __syncthreads();
  const int use_spmask = *use_spmask_p;
  if (tid < 192) {
    int m = tid >> 4, l = tid & 15;
    float* Am = Abuf + m * 196;
    float mx = -1e30f;
    for (int n = l; n < 196; n += 16) mx = fmaxf(mx, Am[n]);
#pragma unroll
    for (int mm = 8; mm; mm >>= 1) mx = fmaxf(mx, __shfl_xor(mx, mm, 64));
    float se = 0.f, mc0 = 0.f, mc1 = 0.f, mc2 = 0.f, mc3 = 0.f;
    for (int n = l; n < 196; n += 16) {
      float e = __expf(Am[n] - mx);
      Am[n] = e;
      se += e;
      int yy = n / 14, xx = n - yy * 14;
      int cell = ((yy >= 7) ? 2 : 0) + ((xx >= 7) ? 1 : 0);
      mc0 += (cell == 0) ? e : 0.f;
      mc1 += (cell == 1) ? e : 0.f;
      mc2 += (cell == 2) ? e : 0.f;
      mc3 += (cell == 3) ? e : 0.f;
    }
#pragma unroll
    for (int mm = 8; mm; mm >>= 1) {
      se += __shfl_xor(se, mm, 64);
      mc0 += __shfl_xor(mc0, mm, 64);
      mc1 += __shfl_xor(mc1, mm, 64);
      mc2 += __shfl_xor(mc2, mm, 64);
      mc3 += __shfl_xor(mc3, mm, 64);
    }
    float invse = 1.0f / se;
    if (use_spmask) {
      int g1 = 0; float bv1 = mc0;
      if (mc1 > bv1) { bv1 = mc1; g1 = 1; }
      if (mc2 > bv1) { bv1 = mc2; g1 = 2; }
      if (mc3 > bv1) { bv1 = mc3; g1 = 3; }
      int g2 = -1; float bv2 = -1e30f;
      if (g1 != 0 && mc0 > bv2) { bv2 = mc0; g2 = 0; }
      if (g1 != 1 && mc1 > bv2) { bv2 = mc1; g2 = 1; }
      if (g1 != 2 && mc2 > bv2) { bv2 = mc2; g2 = 2; }
      if (g1 != 3 && mc3 > bv2) { bv2 = mc3; g2 = 3; }
      float sacc = 0.f;
      for (int n = l; n < 196; n += 16) {
        float a = Am[n] * invse;
        Am[n] = a;
        int yy = n / 14, xx = n - yy * 14;
        int cell = ((yy >= 7) ? 2 : 0) + ((xx >= 7) ? 1 : 0);
        sacc += (cell == g1 || cell == g2) ? a : 0.f;
      }
#pragma unroll
      for (int mm = 8; mm; mm >>= 1) sacc += __shfl_xor(sacc, mm, 64);
      float invs = 1.0f / fmaxf(sacc, 1e-8f);
      float m2acc = 0.f;
      for (int n = l; n < 196; n += 16) {
        int yy = n / 14, xx = n - yy * 14;
        int cell = ((yy >= 7) ? 2 : 0) + ((xx >= 7) ? 1 : 0);
        float a = (cell == g1 || cell == g2) ? (Am[n] * invs) : 0.f;
        Am[n] = a;
        m2acc += a;
      }
#pragma unroll
      for (int mm = 8; mm; mm >>= 1) m2acc += __shfl_xor(m2acc, mm, 64);
      if (l == 0) M2[m] = m2acc;
    } else {
      for (int n = l; n < 196; n += 16) Am[n] *= invse;
      if (l == 0) M2[m] = mx + logf(se);
    }
  }
  __syncthreads();
  if (tid == 0) {
    float mean = 0.f;
    for (int m = 0; m < 12; ++m) mean += M2[m];
    mean *= (1.0f / 12.0f);
    float zmax = -1e30f;
    for (int m = 0; m < 12; ++m) {
      float z = (M2[m] - mean) * 2.0f;
      Pv[m] = z;
      zmax = fmaxf(zmax, z);
    }
    float seP = 0.f;
    for (int m = 0; m < 12; ++m) {
      float e = __expf(Pv[m] - zmax);
      Pv[m] = e;
      seP += e;
    }
    float invP = 1.0f / seP;
    float sump = 0.f;
    for (int m = 0; m < 12; ++m) {
      float p = Pv[m] * invP;
      Pv[m] = p;
      sump += p;
    }
    ZS[0] = sump;
  }
  __syncthreads();
  for (int i = tid; i < 768; i += 256) {
    int m = i >> 6, c = i & 63;
    float a2 = 0.f;
    const float* Am = Abuf + m * 196;
    for (int n = 0; n < 196; ++n) a2 += Am[n] * TOK[SWi(n, c)];
    SQS[m * 64 + c] = a2;
  }
  __syncthreads();
  if (tid < 192) {
    int m = tid >> 4, l = tid & 15;
    float ss = 0.f;
#pragma unroll
    for (int c = l; c < 64; c += 16) {
      float v = SQS[m * 64 + c];
      ss += v * v;
    }
#pragma unroll
    for (int mm = 8; mm; mm >>= 1) ss += __shfl_xor(ss, mm, 64);
    if (l == 0) ISN[m] = 1.0f / fmaxf(sqrtf(ss), 1e-12f);
  }
  __syncthreads();
  if (tid < 64) {
    float v = 0.f;
#pragma unroll
    for (int m = 0; m < 12; ++m) v += Pv[m] * ISN[m] * SQS[m * 64 + tid];
    VV[tid] = v;
  }
  __syncthreads();
  if (tid < 47) {
    float a2 = 0.f;
#pragma unroll
    for (int q = 0; q < 16; ++q) {
      float4 w = *(const float4*)&cls_w[tid * 64 + q * 4];
      float4 v = *(const float4*)&VV[q * 4];
      a2 += w.x * v.x + w.y * v.y + w.z * v.z + w.w * v.w;
    }
    out[(size_t)b * 47 + tid] = a2 + cls_b[tid] * ZS[0];
  }
}

// ---------------------------------------------------------------------------
extern "C" void kernel_launch(void* const* d_in, const int* in_sizes, int n_in,
                              void* d_out, int out_size, void* d_ws, size_t ws_size,
                              hipStream_t stream) {
  (void)n_in; (void)out_size; (void)ws_size;
  const float* x      = (const float*)d_in[0];
  const float* conv_w = (const float*)d_in[1];
  const float* proj_w = (const float*)d_in[2];
  const float* proj_b = (const float*)d_in[3];
  const float* ln1_g  = (const float*)d_in[4];
  const float* ln1_b  = (const float*)d_in[5];
  const float* Wqkv   = (const float*)d_in[6];
  const float* bqkv   = (const float*)d_in[7];
  const float* Wo     = (const float*)d_in[8];
  const float* bo     = (const float*)d_in[9];
  const float* ln2_g  = (const float*)d_in[10];
  const float* ln2_b  = (const float*)d_in[11];
  const float* W1     = (const float*)d_in[12];
  const float* b1     = (const float*)d_in[13];
  const float* W2     = (const float*)d_in[14];
  const float* b2     = (const float*)d_in[15];
  const float* tln_g  = (const float*)d_in[16];
  const float* tln_b  = (const float*)d_in[17];
  const float* slot_q = (const float*)d_in[18];
  const float* cls_w  = (const float*)d_in[19];
  const float* cls_b  = (const float*)d_in[20];
  const int* use_spm  = (const int*)d_in[21];
  const int* spgrid   = (const int*)d_in[22];

  const int B = in_sizes[0] / 784;
  half_t* wsh = (half_t*)d_ws;
  const half8* WQ8 = (const half8*)wsh;                 // 24 units
  const half8* W18 = (const half8*)(wsh + 12288);       // 32 units
  const half8* W28 = (const half8*)(wsh + 28672);       // 32 units
  const half8* Wc8 = (const half8*)(wsh + 45056);       // 30 units
  const half4* WO4 = (const half4*)(wsh + 60416);       // 16 units
  const half4* Pw4 = (const half4*)(wsh + 64512);       // 40 units
  float* tokens = (float*)((char*)d_ws + 163840);

  k_prepack<<<22, 512, 0, stream>>>(conv_w, proj_w, Wqkv, Wo, W1, W2, wsh);

  const int shnet = 48128;
  (void)hipFuncSetAttribute((const void*)k_net,
                            hipFuncAttributeMaxDynamicSharedMemorySize, shnet);
  k_net<<<B, 512, shnet, stream>>>(x, WQ8, W18, W28, Wc8, WO4, Pw4, proj_b,
                                   ln1_g, ln1_b, bqkv, bo, ln2_g, ln2_b,
                                   b1, b2, tln_g, tln_b, tokens);

  k_slots<<<B, 256, 0, stream>>>(tokens, slot_q, cls_w, cls_b, use_spm, spgrid,
                                 (float*)d_out);
}

// Round 11
// 463.322 us; speedup vs baseline: 1.4231x; 1.4231x over previous
//
#include <hip/hip_runtime.h>
#include <math.h>

typedef _Float16 half_t;
typedef __attribute__((ext_vector_type(4))) _Float16 half4;
typedef __attribute__((ext_vector_type(8))) _Float16 half8;
typedef __attribute__((ext_vector_type(4))) float f32x4;

__device__ __forceinline__ f32x4 MFMA16(half4 a, half4 b, f32x4 c) {
  return __builtin_amdgcn_mfma_f32_16x16x16f16(a, b, c, 0, 0, 0);
}
__device__ __forceinline__ f32x4 MFMA32(half8 a, half8 b, f32x4 c) {
  return __builtin_amdgcn_mfma_f32_16x16x32_f16(a, b, c, 0, 0, 0);
}

#if __has_builtin(__builtin_amdgcn_exp2f)
#define EXP2F(x) __builtin_amdgcn_exp2f(x)
#else
#define EXP2F(x) exp2f(x)
#endif

// XOR swizzle for 64-float f32 rows (quad ^= row&15) — k_slots only
__device__ __forceinline__ int SWi(int row, int col) {
  return (row << 6) | (((((col >> 2) ^ row) & 15)) << 2) | (col & 3);
}
__device__ __forceinline__ int SW4i(int row, int q) {
  return (row << 6) | ((((q ^ row) & 15)) << 2);
}
// f16 rows of 64 cols, 16B units: unit8 ^= row&7
__device__ __forceinline__ int XH8W(int t, int k0) {
  return (t << 6) | ((((k0 >> 3) ^ t) & 7) << 3) | (k0 & 7);
}
__device__ __forceinline__ int XH8R(int t, int u8) {
  return (t << 6) | (((u8 ^ t) & 7) << 3);
}
// f16 rows of 32 cols (FFN hidden), 16B units: unit ^= row&3
__device__ __forceinline__ int HB8W(int t, int h) {
  return (t << 5) | ((((h >> 3) ^ t) & 3) << 3) | (h & 7);
}
__device__ __forceinline__ int HB8R(int t, int u8) {
  return (t << 5) | (((u8 ^ t) & 3) << 3);
}

// fast exact-gelu via Abramowitz-Stegun 7.1.26 erf (|err| <= 1.5e-7)
__device__ __forceinline__ float fast_gelu(float v) {
  float x = 0.70710678118654752f * v;
  float ax = fabsf(x);
  float t = 1.0f / fmaf(0.3275911f, ax, 1.0f);
  float poly = t * fmaf(t, fmaf(t, fmaf(t, fmaf(t, 1.061405429f, -1.453152027f),
                                        1.421413741f), -0.284496736f), 0.254829592f);
  float e = EXP2F(-1.4426950408889634f * ax * ax);
  float erfax = fmaf(-poly, e, 1.0f);
  float er = __builtin_copysignf(erfax, x);
  return 0.5f * v * (1.0f + er);
}

// ---------------------------------------------------------------------------
// prepack: weights -> f16 MFMA fragment order (unchanged).
// h8 units (1024B): lane ln holds row tile*16+(ln&15), k = ks2*32+(ln>>4)*8+j.
//   WQ8[0,24) W18[24,56) W28[56,88) Wc8[88,118)
// h4 units (512B) at half-offset 60416: WO4 16 units, Pw4 40 units.
// ---------------------------------------------------------------------------
__global__ void k_prepack(const float* __restrict__ conv_w,
                          const float* __restrict__ proj_w,
                          const float* __restrict__ Wqkv,
                          const float* __restrict__ Wo,
                          const float* __restrict__ W1,
                          const float* __restrict__ W2,
                          half_t* __restrict__ dst) {
  int id = blockIdx.x * 512 + threadIdx.x;
  if (id < 7552) {
    int unit = id >> 6, ln = id & 63;
    int li = ln & 15, g8 = (ln >> 4) * 8;
    float v[8];
    if (unit < 24) {                     // Wqkv [192][64]
      int rt = unit >> 1, ks2 = unit & 1;
      const float* s = &Wqkv[(rt * 16 + li) * 64 + ks2 * 32 + g8];
#pragma unroll
      for (int r = 0; r < 8; ++r) v[r] = s[r];
    } else if (unit < 56) {              // W1 [256][64]
      int u = unit - 24, rt = u >> 1, ks2 = u & 1;
      const float* s = &W1[(rt * 16 + li) * 64 + ks2 * 32 + g8];
#pragma unroll
      for (int r = 0; r < 8; ++r) v[r] = s[r];
    } else if (unit < 88) {              // W2 [64][256]
      int u = unit - 56, ct = u >> 3, ks2 = u & 7;
      const float* s = &W2[(ct * 16 + li) * 256 + ks2 * 32 + g8];
#pragma unroll
      for (int r = 0; r < 8; ++r) v[r] = s[r];
    } else {                             // conv_w [150][81] pad [160][96]
      int u = unit - 88, ct = u / 3, ks2 = u - ct * 3;
      int row = ct * 16 + li;
#pragma unroll
      for (int r = 0; r < 8; ++r) {
        int col = ks2 * 32 + g8 + r;
        v[r] = (row < 150 && col < 81) ? conv_w[row * 81 + col] : 0.f;
      }
    }
    half8 o;
#pragma unroll
    for (int r = 0; r < 8; ++r) o[r] = (half_t)v[r];
    ((half8*)dst)[id] = o;
  } else if (id < 11136) {
    int id2 = id - 7552;
    int unit = id2 >> 6, ln = id2 & 63;
    int li = ln & 15, gq = (ln >> 4) * 4;
    float v[4];
    if (unit < 16) {                     // Wo [64][64], K=16 frags
      int ct = unit >> 2, h = unit & 3;
      const float* s = &Wo[(ct * 16 + li) * 64 + h * 16 + gq];
#pragma unroll
      for (int r = 0; r < 4; ++r) v[r] = s[r];
    } else {                             // proj_w [64][150] pad [64][160]
      int u = unit - 16, dt = u / 10, ct = u - dt * 10;
#pragma unroll
      for (int r = 0; r < 4; ++r) {
        int col = ct * 16 + gq + r;
        v[r] = (col < 150) ? proj_w[(dt * 16 + li) * 150 + col] : 0.f;
      }
    }
    half4 o;
#pragma unroll
    for (int r = 0; r < 4; ++r) o[r] = (half_t)v[r];
    ((half4*)(dst + 60416))[id2] = o;
  }
}

// ---------------------------------------------------------------------------
// k_net v5: conv -> LN1 -> attn (4 single-head passes) -> LN2 -> FFN (8x32)
// -> tln. Residual in registers; 48,128B LDS.
// launch_bounds(512,4): DO NOT use min-waves=6 — R8/R10 both show it forces a
// 40-VGPR allocation with ~1GB scratch spill traffic. With (512,4) the R9
// measurement is 60 VGPR (no spill); 60 <= 64 keeps the 8-wave VGPR tier, so
// runtime occupancy is LDS-limited: floor(163840/48128) = 3 blocks/CU.
// LDS (bytes): Xh@0 (26,624; xsh 2,520 + OS 34,816 alias)
//   attn: Kb@26,624 (8,320 [208][20])  VT@34,944 (6,784 [16][212])
//   ffn:  W1S@26,624 (4,096) W2S@30,720 (4,096) Hb@34,816 (13,312 [208][32])
// ---------------------------------------------------------------------------
__global__ __launch_bounds__(512, 4) void k_net(
    const float* __restrict__ x,
    const half8* __restrict__ WQ8, const half8* __restrict__ W18,
    const half8* __restrict__ W28, const half8* __restrict__ Wc8,
    const half4* __restrict__ WO4, const half4* __restrict__ Pw4,
    const float* __restrict__ proj_b,
    const float* __restrict__ ln1_g, const float* __restrict__ ln1_b,
    const float* __restrict__ bqkv, const float* __restrict__ bo,
    const float* __restrict__ ln2_g, const float* __restrict__ ln2_b,
    const float* __restrict__ b1, const float* __restrict__ b2,
    const float* __restrict__ tln_g, const float* __restrict__ tln_b,
    float* __restrict__ tokens) {
  extern __shared__ __align__(16) char pool[];
  half_t* xsh = (half_t*)pool;                 // conv phase alias
  half_t* Xh = (half_t*)pool;                  // LN1..FFN [208][64]
  half_t* Kb = (half_t*)(pool + 26624);        // attn: [208][20]
  half_t* VT = (half_t*)(pool + 34944);        // attn: [16][212]
  half8* W1S = (half8*)(pool + 26624);         // ffn alias, 4 units
  half8* W2S = (half8*)(pool + 30720);         // ffn alias, 4 units
  half_t* Hb = (half_t*)(pool + 34816);        // ffn alias [208][32]
  float* OS = (float*)pool;                    // out alias, 8x16x68 f32

  const int b = blockIdx.x, tid = threadIdx.x;
  const int wv = tid >> 6, ln = tid & 63, g = ln >> 4, li = ln & 15;
  const size_t base = (size_t)b * 12544;

  f32x4 res[2][4];
#pragma unroll
  for (int qi = 0; qi < 2; ++qi)
#pragma unroll
    for (int ct = 0; ct < 4; ++ct) res[qi][ct] = f32x4{0.f, 0.f, 0.f, 0.f};

  // ---- conv phase: stage image as f16 ----
  for (int i = tid; i < 1260; i += 512) xsh[i] = (half_t)0.f;
  __syncthreads();
  for (int i = tid; i < 784; i += 512) {
    int r = i / 28, c = i - r * 28;
    xsh[(r + 4) * 36 + c + 4] = (half_t)x[b * 784 + i];
  }
  __syncthreads();

#pragma unroll
  for (int qi = 0; qi < 2; ++qi) {
    int qt = wv + 8 * qi;
    if (qt < 13) {
      int pp = qt * 16 + li;
      int pc = (pp < 196) ? pp : 195;
      int oy = pc / 14, ox = pc - oy * 14;
      int pbase = oy * 72 + ox * 2;
      half8 bf[3];
#pragma unroll
      for (int ks2 = 0; ks2 < 3; ++ks2) {
#pragma unroll
        for (int j = 0; j < 8; ++j) {
          int tap = ks2 * 32 + g * 8 + j;   // 0..95, valid <= 80
          half_t v = (half_t)0.f;
          if (tap <= 80) {
            int ky = tap / 9;
            v = xsh[pbase + ky * 27 + tap];
          }
          bf[ks2][j] = v;
        }
      }
      // ct-outer / dt-inner: only ONE hf fragment live (register pressure)
#pragma unroll
      for (int ct = 0; ct < 10; ++ct) {
        f32x4 acc = {0.f, 0.f, 0.f, 0.f};
#pragma unroll
        for (int ks2 = 0; ks2 < 3; ++ks2)
          acc = MFMA32(Wc8[(ct * 3 + ks2) * 64 + ln], bf[ks2], acc);
        half4 hf;
#pragma unroll
        for (int r = 0; r < 4; ++r) hf[r] = (half_t)fast_gelu(acc[r]);
#pragma unroll
        for (int dt = 0; dt < 4; ++dt)
          res[qi][dt] = MFMA16(Pw4[(dt * 10 + ct) * 64 + ln], hf, res[qi][dt]);
      }
#pragma unroll
      for (int dt = 0; dt < 4; ++dt) {
        float4 pb4 = *(const float4*)&proj_b[dt * 16 + g * 4];
        res[qi][dt][0] += pb4.x; res[qi][dt][1] += pb4.y;
        res[qi][dt][2] += pb4.z; res[qi][dt][3] += pb4.w;
      }
    }
  }
  __syncthreads();   // xsh done; Xh region free

  // ---- LN1 (in-register) -> Xh ----
  for (int i = tid; i < 768; i += 512)
    Xh[(196 + (i >> 6)) * 64 + (i & 63)] = (half_t)0.f;
#pragma unroll
  for (int qi = 0; qi < 2; ++qi) {
    int qt = wv + 8 * qi;
    if (qt < 13) {
      float sum = 0.f;
#pragma unroll
      for (int ct = 0; ct < 4; ++ct)
#pragma unroll
        for (int r = 0; r < 4; ++r) sum += res[qi][ct][r];
      sum += __shfl_xor(sum, 16, 64);
      sum += __shfl_xor(sum, 32, 64);
      float mu = sum * 0.015625f;
      float vs = 0.f;
#pragma unroll
      for (int ct = 0; ct < 4; ++ct)
#pragma unroll
        for (int r = 0; r < 4; ++r) { float d = res[qi][ct][r] - mu; vs += d * d; }
      vs += __shfl_xor(vs, 16, 64);
      vs += __shfl_xor(vs, 32, 64);
      float rs = rsqrtf(vs * 0.015625f + 1e-5f);
      int t = qt * 16 + li;
      if (t < 196) {
#pragma unroll
        for (int ct = 0; ct < 4; ++ct) {
          int k0 = ct * 16 + g * 4;
          float4 gg = *(const float4*)&ln1_g[k0];
          float4 bb = *(const float4*)&ln1_b[k0];
          half4 o;
          o[0] = (half_t)((res[qi][ct][0] - mu) * rs * gg.x + bb.x);
          o[1] = (half_t)((res[qi][ct][1] - mu) * rs * gg.y + bb.y);
          o[2] = (half_t)((res[qi][ct][2] - mu) * rs * gg.z + bb.z);
          o[3] = (half_t)((res[qi][ct][3] - mu) * rs * gg.w + bb.w);
          *(half4*)&Xh[XH8W(t, k0)] = o;
        }
      }
    }
  }
  __syncthreads();

  // ---- Q fragments for all 4 heads (scale folds 1/4*log2e) ----
  half4 qf[2][4];
#pragma unroll
  for (int qi = 0; qi < 2; ++qi) {
    int qt = wv + 8 * qi;
    if (qt < 13) {
#pragma unroll
      for (int h = 0; h < 4; ++h) {
        f32x4 acc = {0.f, 0.f, 0.f, 0.f};
#pragma unroll
        for (int ks2 = 0; ks2 < 2; ++ks2)
          acc = MFMA32(WQ8[(h * 2 + ks2) * 64 + ln],
                       *(const half8*)&Xh[XH8R(qt * 16 + li, ks2 * 4 + g)], acc);
#pragma unroll
        for (int r = 0; r < 4; ++r)
          qf[qi][h][r] = (half_t)((acc[r] + bqkv[h * 16 + g * 4 + r]) *
                                  0.36067376022224085f);
      }
    }
  }

  // ---- attention: 4 single-head passes ----
  for (int h = 0; h < 4; ++h) {
    if (wv < 4) {   // K staging (waves 0-3)
      half8 af[2];
#pragma unroll
      for (int ks2 = 0; ks2 < 2; ++ks2)
        af[ks2] = WQ8[((4 + h) * 2 + ks2) * 64 + ln];
      float bias[4];
#pragma unroll
      for (int r = 0; r < 4; ++r) bias[r] = bqkv[64 + h * 16 + g * 4 + r];
      for (int tt = wv; tt < 13; tt += 4) {
        int trow = tt * 16 + li;
        f32x4 acc = {0.f, 0.f, 0.f, 0.f};
#pragma unroll
        for (int ks2 = 0; ks2 < 2; ++ks2)
          acc = MFMA32(af[ks2], *(const half8*)&Xh[XH8R(trow, ks2 * 4 + g)], acc);
#pragma unroll
        for (int r = 0; r < 4; ++r)
          Kb[trow * 20 + g * 4 + r] = (half_t)(acc[r] + bias[r]);
      }
    } else {        // V^T staging (waves 4-7)
      half8 af[2];
#pragma unroll
      for (int ks2 = 0; ks2 < 2; ++ks2)
        af[ks2] = WQ8[((8 + h) * 2 + ks2) * 64 + ln];
      float bias[4];
#pragma unroll
      for (int r = 0; r < 4; ++r) bias[r] = bqkv[128 + h * 16 + g * 4 + r];
      for (int tt = wv - 4; tt < 13; tt += 4) {
        int trow = tt * 16 + li;
        f32x4 acc = {0.f, 0.f, 0.f, 0.f};
#pragma unroll
        for (int ks2 = 0; ks2 < 2; ++ks2)
          acc = MFMA32(af[ks2], *(const half8*)&Xh[XH8R(trow, ks2 * 4 + g)], acc);
#pragma unroll
        for (int r = 0; r < 4; ++r)
          VT[(g * 4 + r) * 212 + trow] = (half_t)(acc[r] + bias[r]);
      }
    }
    __syncthreads();
    // streamed QK^T -> exp2 (no max-subtract; scores bounded) -> PV -> Wo
#pragma unroll
    for (int qi = 0; qi < 2; ++qi) {
      int qt = wv + 8 * qi;
      if (qt < 13) {
        float es = 0.f;
        f32x4 oa = {0.f, 0.f, 0.f, 0.f};
#pragma unroll
        for (int nt = 0; nt < 13; ++nt) {
          f32x4 zz = {0.f, 0.f, 0.f, 0.f};
          f32x4 sv = MFMA16(*(const half4*)&Kb[(nt * 16 + li) * 20 + g * 4],
                            qf[qi][h], zz);
          if (nt == 12 && g > 0) { sv[0] = -3e38f; sv[1] = -3e38f; sv[2] = -3e38f; sv[3] = -3e38f; }
          half4 pf;
#pragma unroll
          for (int r = 0; r < 4; ++r) {
            float e = EXP2F(sv[r]);
            es += e;
            pf[r] = (half_t)e;
          }
          oa = MFMA16(*(const half4*)&VT[li * 212 + nt * 16 + g * 4], pf, oa);
        }
        es += __shfl_xor(es, 16, 64);
        es += __shfl_xor(es, 32, 64);
        float inv = 1.0f / es;
        half4 of;
#pragma unroll
        for (int r = 0; r < 4; ++r) of[r] = (half_t)(oa[r] * inv);
#pragma unroll
        for (int ct = 0; ct < 4; ++ct)
          res[qi][ct] = MFMA16(WO4[(ct * 4 + h) * 64 + ln], of, res[qi][ct]);
      }
    }
    __syncthreads();
  }
  // + bo
#pragma unroll
  for (int qi = 0; qi < 2; ++qi) {
    int qt = wv + 8 * qi;
    if (qt < 13) {
#pragma unroll
      for (int ct = 0; ct < 4; ++ct) {
        float4 bb = *(const float4*)&bo[ct * 16 + g * 4];
        res[qi][ct][0] += bb.x; res[qi][ct][1] += bb.y;
        res[qi][ct][2] += bb.z; res[qi][ct][3] += bb.w;
      }
    }
  }

  // ---- LN2 -> Xh ----
#pragma unroll
  for (int qi = 0; qi < 2; ++qi) {
    int qt = wv + 8 * qi;
    if (qt < 13) {
      float sum = 0.f;
#pragma unroll
      for (int ct = 0; ct < 4; ++ct)
#pragma unroll
        for (int r = 0; r < 4; ++r) sum += res[qi][ct][r];
      sum += __shfl_xor(sum, 16, 64);
      sum += __shfl_xor(sum, 32, 64);
      float mu = sum * 0.015625f;
      float vs = 0.f;
#pragma unroll
      for (int ct = 0; ct < 4; ++ct)
#pragma unroll
        for (int r = 0; r < 4; ++r) { float d = res[qi][ct][r] - mu; vs += d * d; }
      vs += __shfl_xor(vs, 16, 64);
      vs += __shfl_xor(vs, 32, 64);
      float rs = rsqrtf(vs * 0.015625f + 1e-5f);
      int t = qt * 16 + li;
      if (t < 196) {
#pragma unroll
        for (int ct = 0; ct < 4; ++ct) {
          int k0 = ct * 16 + g * 4;
          float4 gg = *(const float4*)&ln2_g[k0];
          float4 bb = *(const float4*)&ln2_b[k0];
          half4 o;
          o[0] = (half_t)((res[qi][ct][0] - mu) * rs * gg.x + bb.x);
          o[1] = (half_t)((res[qi][ct][1] - mu) * rs * gg.y + bb.y);
          o[2] = (half_t)((res[qi][ct][2] - mu) * rs * gg.z + bb.z);
          o[3] = (half_t)((res[qi][ct][3] - mu) * rs * gg.w + bb.w);
          *(half4*)&Xh[XH8W(t, k0)] = o;
        }
      }
    }
  }
  __syncthreads();

  // ---- FFN: 8 chunks of 32 hidden ----
  for (int ch = 0; ch < 8; ++ch) {
    if (tid < 256) {
      int u = tid >> 6, l2 = tid & 63;       // u = lnt*2+ks2
      int lnt = u >> 1, ks2 = u & 1;
      W1S[u * 64 + l2] = W18[((ch * 2 + lnt) * 2 + ks2) * 64 + l2];
    } else {
      int i2 = tid - 256;
      int ct = i2 >> 6, l2 = i2 & 63;
      W2S[ct * 64 + l2] = W28[(ct * 8 + ch) * 64 + l2];
    }
    __syncthreads();
    // H = gelu(t2 @ W1^T + b1): 26 units (13 mt x 2 lnt)
    for (int u = wv; u < 26; u += 8) {
      int mt = u >> 1, lnt = u & 1;
      f32x4 acc = {0.f, 0.f, 0.f, 0.f};
#pragma unroll
      for (int ks2 = 0; ks2 < 2; ++ks2)
        acc = MFMA32(*(const half8*)&Xh[XH8R(mt * 16 + li, ks2 * 4 + g)],
                     W1S[(lnt * 2 + ks2) * 64 + ln], acc);
      float bb = b1[ch * 32 + lnt * 16 + li];
#pragma unroll
      for (int r = 0; r < 4; ++r)
        Hb[HB8W(mt * 16 + g * 4 + r, lnt * 16 + li)] = (half_t)fast_gelu(acc[r] + bb);
    }
    __syncthreads();
    // res += W2 @ H  (K=32 over the chunk's hidden dims)
#pragma unroll
    for (int qi = 0; qi < 2; ++qi) {
      int qt = wv + 8 * qi;
      if (qt < 13) {
#pragma unroll
        for (int ct = 0; ct < 4; ++ct)
          res[qi][ct] = MFMA32(W2S[ct * 64 + ln],
                               *(const half8*)&Hb[HB8R(qt * 16 + li, g)],
                               res[qi][ct]);
      }
    }
    __syncthreads();
  }
  // + b2
#pragma unroll
  for (int qi = 0; qi < 2; ++qi) {
    int qt = wv + 8 * qi;
    if (qt < 13) {
#pragma unroll
      for (int ct = 0; ct < 4; ++ct) {
        float4 bb = *(const float4*)&b2[ct * 16 + g * 4];
        res[qi][ct][0] += bb.x; res[qi][ct][1] += bb.y;
        res[qi][ct][2] += bb.z; res[qi][ct][3] += bb.w;
      }
    }
  }

  // ---- final LN -> per-wave OS staging -> coalesced store (no barrier) ----
#pragma unroll
  for (int qi = 0; qi < 2; ++qi) {
    int qt = wv + 8 * qi;
    if (qt < 13) {
      float sum = 0.f;
#pragma unroll
      for (int ct = 0; ct < 4; ++ct)
#pragma unroll
        for (int r = 0; r < 4; ++r) sum += res[qi][ct][r];
      sum += __shfl_xor(sum, 16, 64);
      sum += __shfl_xor(sum, 32, 64);
      float mu = sum * 0.015625f;
      float vs = 0.f;
#pragma unroll
      for (int ct = 0; ct < 4; ++ct)
#pragma unroll
        for (int r = 0; r < 4; ++r) { float d = res[qi][ct][r] - mu; vs += d * d; }
      vs += __shfl_xor(vs, 16, 64);
      vs += __shfl_xor(vs, 32, 64);
      float rs = rsqrtf(vs * 0.015625f + 1e-5f);
#pragma unroll
      for (int ct = 0; ct < 4; ++ct) {
        float4 gg = *(const float4*)&tln_g[ct * 16 + g * 4];
        float4 bb = *(const float4*)&tln_b[ct * 16 + g * 4];
        float4 o;
        o.x = (res[qi][ct][0] - mu) * rs * gg.x + bb.x;
        o.y = (res[qi][ct][1] - mu) * rs * gg.y + bb.y;
        o.z = (res[qi][ct][2] - mu) * rs * gg.z + bb.z;
        o.w = (res[qi][ct][3] - mu) * rs * gg.w + bb.w;
        *(float4*)&OS[wv * 1088 + li * 68 + ct * 16 + g * 4] = o;
      }
#pragma unroll
      for (int rep = 0; rep < 4; ++rep) {
        int r4 = rep * 64 + ln;
        int row = r4 >> 4, q = r4 & 15;
        int pp = qt * 16 + row;
        if (pp < 196)
          *(float4*)&tokens[base + (size_t)pp * 64 + q * 4] =
              *(const float4*)&OS[wv * 1088 + row * 68 + q * 4];
      }
    }
  }
}

// ---------------------------------------------------------------------------
// slots: plain load (tln applied) + slot attention + spmask + classifier (f32)
// ---------------------------------------------------------------------------
__global__ __launch_bounds__(256) void k_slots(
    const float* __restrict__ tokens, const float* __restrict__ slot_q,
    const float* __restrict__ cls_w, const float* __restrict__ cls_b,
    const int* __restrict__ use_spmask_p, const int* __restrict__ grid_p,
    float* __restrict__ out) {
  __shared__ float TOK[12544];
  __shared__ float Abuf[12 * 196];
  __shared__ float SQS[12 * 64];
  __shared__ float INV[196];
  __shared__ float VV[64];
  __shared__ float Pv[12];
  __shared__ float M2[12];
  __shared__ float ISN[12];
  __shared__ float ZS[2];

  const int b = blockIdx.x, tid = threadIdx.x;
  const size_t base = (size_t)b * 12544;
  (void)grid_p;

  for (int i = tid; i < 12544; i += 256) {
    int t = i >> 6, c = i & 63;
    TOK[SWi(t, c)] = tokens[base + i];
  }
  __syncthreads();
  if (tid < 196) {
    float ss = 0.f;
#pragma unroll
    for (int q = 0; q < 16; ++q) {
      float4 v = *(const float4*)&TOK[SW4i(tid, q)];
      ss += v.x * v.x + v.y * v.y + v.z * v.z + v.w * v.w;
    }
    INV[tid] = 1.0f / fmaxf(sqrtf(ss), 1e-12f);
  }
  if (tid < 192) {
    int m = tid >> 4, l = tid & 15;
    float ss = 0.f;
#pragma unroll
    for (int c = l; c < 64; c += 16) {
      float v = slot_q[m * 64 + c];
      ss += v * v;
    }
#pragma unroll
    for (int mm = 8; mm; mm >>= 1) ss += __shfl_xor(ss, mm, 64);
    float invq = 1.0f / fmaxf(sqrtf(ss), 1e-12f);
#pragma unroll
    for (int c = l; c < 64; c += 16) SQS[m * 64 + c] = slot_q[m * 64 + c] * invq;
  }
  __syncthreads();
  for (int i = tid; i < 2352; i += 256) {
    int m = i / 196, n = i - m * 196;
    float d = 0.f;
#pragma unroll
    for (int q = 0; q < 16; ++q) {
      float4 tv = *(const float4*)&TOK[SW4i(n, q)];
      float4 sv = *(const float4*)&SQS[m * 64 + q * 4];
      d += tv.x * sv.x + tv.y * sv.y + tv.z * sv.z + tv.w * sv.w;
    }
    Abuf[i] = d * INV[n] * 0.125f;
  }
  __syncthreads();
  const int use_spmask = *use_spmask_p;
  if (tid < 192) {
    int m = tid >> 4, l = tid & 15;
    float* Am = Abuf + m * 196;
    float mx = -1e30f;
    for (int n = l; n < 196; n += 16) mx = fmaxf(mx, Am[n]);
#pragma unroll
    for (int mm = 8; mm; mm >>= 1) mx = fmaxf(mx, __shfl_xor(mx, mm, 64));
    float se = 0.f, mc0 = 0.f, mc1 = 0.f, mc2 = 0.f, mc3 = 0.f;
    for (int n = l; n < 196; n += 16) {
      float e = __expf(Am[n] - mx);
      Am[n] = e;
      se += e;
      int yy = n / 14, xx = n - yy * 14;
      int cell = ((yy >= 7) ? 2 : 0) + ((xx >= 7) ? 1 : 0);
      mc0 += (cell == 0) ? e : 0.f;
      mc1 += (cell == 1) ? e : 0.f;
      mc2 += (cell == 2) ? e : 0.f;
      mc3 += (cell == 3) ? e : 0.f;
    }
#pragma unroll
    for (int mm = 8; mm; mm >>= 1) {
      se += __shfl_xor(se, mm, 64);
      mc0 += __shfl_xor(mc0, mm, 64);
      mc1 += __shfl_xor(mc1, mm, 64);
      mc2 += __shfl_xor(mc2, mm, 64);
      mc3 += __shfl_xor(mc3, mm, 64);
    }
    float invse = 1.0f / se;
    if (use_spmask) {
      int g1 = 0; float bv1 = mc0;
      if (mc1 > bv1) { bv1 = mc1; g1 = 1; }
      if (mc2 > bv1) { bv1 = mc2; g1 = 2; }
      if (mc3 > bv1) { bv1 = mc3; g1 = 3; }
      int g2 = -1; float bv2 = -1e30f;
      if (g1 != 0 && mc0 > bv2) { bv2 = mc0; g2 = 0; }
      if (g1 != 1 && mc1 > bv2) { bv2 = mc1; g2 = 1; }
      if (g1 != 2 && mc2 > bv2) { bv2 = mc2; g2 = 2; }
      if (g1 != 3 && mc3 > bv2) { bv2 = mc3; g2 = 3; }
      float sacc = 0.f;
      for (int n = l; n < 196; n += 16) {
        float a = Am[n] * invse;
        Am[n] = a;
        int yy = n / 14, xx = n - yy * 14;
        int cell = ((yy >= 7) ? 2 : 0) + ((xx >= 7) ? 1 : 0);
        sacc += (cell == g1 || cell == g2) ? a : 0.f;
      }
#pragma unroll
      for (int mm = 8; mm; mm >>= 1) sacc += __shfl_xor(sacc, mm, 64);
      float invs = 1.0f / fmaxf(sacc, 1e-8f);
      float m2acc = 0.f;
      for (int n = l; n < 196; n += 16) {
        int yy = n / 14, xx = n - yy * 14;
        int cell = ((yy >= 7) ? 2 : 0) + ((xx >= 7) ? 1 : 0);
        float a = (cell == g1 || cell == g2) ? (Am[n] * invs) : 0.f;
        Am[n] = a;
        m2acc += a;
      }
#pragma unroll
      for (int mm = 8; mm; mm >>= 1) m2acc += __shfl_xor(m2acc, mm, 64);
      if (l == 0) M2[m] = m2acc;
    } else {
      for (int n = l; n < 196; n += 16) Am[n] *= invse;
      if (l == 0) M2[m] = mx + logf(se);
    }
  }
  __syncthreads();
  if (tid == 0) {
    float mean = 0.f;
    for (int m = 0; m < 12; ++m) mean += M2[m];
    mean *= (1.0f / 12.0f);
    float zmax = -1e30f;
    for (int m = 0; m < 12; ++m) {
      float z = (M2[m] - mean) * 2.0f;
      Pv[m] = z;
      zmax = fmaxf(zmax, z);
    }
    float seP = 0.f;
    for (int m = 0; m < 12; ++m) {
      float e = __expf(Pv[m] - zmax);
      Pv[m] = e;
      seP += e;
    }
    float invP = 1.0f / seP;
    float sump = 0.f;
    for (int m = 0; m < 12; ++m) {
      float p = Pv[m] * invP;
      Pv[m] = p;
      sump += p;
    }
    ZS[0] = sump;
  }
  __syncthreads();
  for (int i = tid; i < 768; i += 256) {
    int m = i >> 6, c = i & 63;
    float a2 = 0.f;
    const float* Am = Abuf + m * 196;
    for (int n = 0; n < 196; ++n) a2 += Am[n] * TOK[SWi(n, c)];
    SQS[m * 64 + c] = a2;
  }
  __syncthreads();
  if (tid < 192) {
    int m = tid >> 4, l = tid & 15;
    float ss = 0.f;
#pragma unroll
    for (int c = l; c < 64; c += 16) {
      float v = SQS[m * 64 + c];
      ss += v * v;
    }
#pragma unroll
    for (int mm = 8; mm; mm >>= 1) ss += __shfl_xor(ss, mm, 64);
    if (l == 0) ISN[m] = 1.0f / fmaxf(sqrtf(ss), 1e-12f);
  }
  __syncthreads();
  if (tid < 64) {
    float v = 0.f;
#pragma unroll
    for (int m = 0; m < 12; ++m) v += Pv[m] * ISN[m] * SQS[m * 64 + tid];
    VV[tid] = v;
  }
  __syncthreads();
  if (tid < 47) {
    float a2 = 0.f;
#pragma unroll
    for (int q = 0; q < 16; ++q) {
      float4 w = *(const float4*)&cls_w[tid * 64 + q * 4];
      float4 v = *(const float4*)&VV[q * 4];
      a2 += w.x * v.x + w.y * v.y + w.z * v.z + w.w * v.w;
    }
    out[(size_t)b * 47 + tid] = a2 + cls_b[tid] * ZS[0];
  }
}

// ---------------------------------------------------------------------------
extern "C" void kernel_launch(void* const* d_in, const int* in_sizes, int n_in,
                              void* d_out, int out_size, void* d_ws, size_t ws_size,
                              hipStream_t stream) {
  (void)n_in; (void)out_size; (void)ws_size;
  const float* x      = (const float*)d_in[0];
  const float* conv_w = (const float*)d_in[1];
  const float* proj_w = (const float*)d_in[2];
  const float* proj_b = (const float*)d_in[3];
  const float* ln1_g  = (const float*)d_in[4];
  const float* ln1_b  = (const float*)d_in[5];
  const float* Wqkv   = (const float*)d_in[6];
  const float* bqkv   = (const float*)d_in[7];
  const float* Wo     = (const float*)d_in[8];
  const float* bo     = (const float*)d_in[9];
  const float* ln2_g  = (const float*)d_in[10];
  const float* ln2_b  = (const float*)d_in[11];
  const float* W1     = (const float*)d_in[12];
  const float* b1     = (const float*)d_in[13];
  const float* W2     = (const float*)d_in[14];
  const float* b2     = (const float*)d_in[15];
  const float* tln_g  = (const float*)d_in[16];
  const float* tln_b  = (const float*)d_in[17];
  const float* slot_q = (const float*)d_in[18];
  const float* cls_w  = (const float*)d_in[19];
  const float* cls_b  = (const float*)d_in[20];
  const int* use_spm  = (const int*)d_in[21];
  const int* spgrid   = (const int*)d_in[22];

  const int B = in_sizes[0] / 784;
  half_t* wsh = (half_t*)d_ws;
  const half8* WQ8 = (const half8*)wsh;                 // 24 units
  const half8* W18 = (const half8*)(wsh + 12288);       // 32 units
  const half8* W28 = (const half8*)(wsh + 28672);       // 32 units
  const half8* Wc8 = (const half8*)(wsh + 45056);       // 30 units
  const half4* WO4 = (const half4*)(wsh + 60416);       // 16 units
  const half4* Pw4 = (const half4*)(wsh + 64512);       // 40 units
  float* tokens = (float*)((char*)d_ws + 163840);

  k_prepack<<<22, 512, 0, stream>>>(conv_w, proj_w, Wqkv, Wo, W1, W2, wsh);

  const int shnet = 48128;
  (void)hipFuncSetAttribute((const void*)k_net,
                            hipFuncAttributeMaxDynamicSharedMemorySize, shnet);
  k_net<<<B, 512, shnet, stream>>>(x, WQ8, W18, W28, Wc8, WO4, Pw4, proj_b,
                                   ln1_g, ln1_b, bqkv, bo, ln2_g, ln2_b,
                                   b1, b2, tln_g, tln_b, tokens);

  k_slots<<<B, 256, 0, stream>>>(tokens, slot_q, cls_w, cls_b, use_spm, spgrid,
                                 (float*)d_out);
}

// Round 13
// 399.807 us; speedup vs baseline: 1.6492x; 1.1589x over previous
//
#include <hip/hip_runtime.h>
#include <math.h>

typedef _Float16 half_t;
typedef __attribute__((ext_vector_type(2))) _Float16 half2t;
typedef __attribute__((ext_vector_type(4))) _Float16 half4;
typedef __attribute__((ext_vector_type(8))) _Float16 half8;
typedef __attribute__((ext_vector_type(4))) float f32x4;

__device__ __forceinline__ f32x4 MFMA16(half4 a, half4 b, f32x4 c) {
  return __builtin_amdgcn_mfma_f32_16x16x16f16(a, b, c, 0, 0, 0);
}
__device__ __forceinline__ f32x4 MFMA32(half8 a, half8 b, f32x4 c) {
  return __builtin_amdgcn_mfma_f32_16x16x32_f16(a, b, c, 0, 0, 0);
}

#if __has_builtin(__builtin_amdgcn_exp2f)
#define EXP2F(x) __builtin_amdgcn_exp2f(x)
#else
#define EXP2F(x) exp2f(x)
#endif

// packed f32x2 -> f16x2 (v_cvt_pkrtz_f16_f32, single VALU op).
// NOTE: the builtin returns __fp16x2, a distinct clang type from _Float16x2 —
// bit_cast it (same bits, no extra instruction).
__device__ __forceinline__ half2t cvt_pk(float a, float b) {
#if __has_builtin(__builtin_amdgcn_cvt_pkrtz)
  return __builtin_bit_cast(half2t, __builtin_amdgcn_cvt_pkrtz(a, b));
#else
  half2t r; r[0] = (half_t)a; r[1] = (half_t)b; return r;
#endif
}
__device__ __forceinline__ half4 PK4(float a, float b, float c, float d) {
  half2t lo = cvt_pk(a, b), hi = cvt_pk(c, d);
  return __builtin_shufflevector(lo, hi, 0, 1, 2, 3);
}

// XOR swizzle for 64-float f32 rows (quad ^= row&15) — k_slots only
__device__ __forceinline__ int SWi(int row, int col) {
  return (row << 6) | (((((col >> 2) ^ row) & 15)) << 2) | (col & 3);
}
__device__ __forceinline__ int SW4i(int row, int q) {
  return (row << 6) | ((((q ^ row) & 15)) << 2);
}
// f16 rows of 64 cols, 16B units: unit8 ^= row&7
__device__ __forceinline__ int XH8W(int t, int k0) {
  return (t << 6) | ((((k0 >> 3) ^ t) & 7) << 3) | (k0 & 7);
}
__device__ __forceinline__ int XH8R(int t, int u8) {
  return (t << 6) | (((u8 ^ t) & 7) << 3);
}

// fast exact-gelu via Abramowitz-Stegun 7.1.26 erf (|err| <= 1.5e-7)
__device__ __forceinline__ float fast_gelu(float v) {
  float x = 0.70710678118654752f * v;
  float ax = fabsf(x);
  float t = 1.0f / fmaf(0.3275911f, ax, 1.0f);
  float poly = t * fmaf(t, fmaf(t, fmaf(t, fmaf(t, 1.061405429f, -1.453152027f),
                                        1.421413741f), -0.284496736f), 0.254829592f);
  float e = EXP2F(-1.4426950408889634f * ax * ax);
  float erfax = fmaf(-poly, e, 1.0f);
  float er = __builtin_copysignf(erfax, x);
  return 0.5f * v * (1.0f + er);
}

// ---------------------------------------------------------------------------
// prepack: weights -> f16 MFMA fragment order (unchanged).
// h8 units (1024B): lane ln holds row tile*16+(ln&15), k = ks2*32+(ln>>4)*8+j.
//   WQ8[0,24) W18[24,56) W28[56,88) Wc8[88,118)
// h4 units (512B) at half-offset 60416: WO4 16 units, Pw4 40 units.
// ---------------------------------------------------------------------------
__global__ void k_prepack(const float* __restrict__ conv_w,
                          const float* __restrict__ proj_w,
                          const float* __restrict__ Wqkv,
                          const float* __restrict__ Wo,
                          const float* __restrict__ W1,
                          const float* __restrict__ W2,
                          half_t* __restrict__ dst) {
  int id = blockIdx.x * 512 + threadIdx.x;
  if (id < 7552) {
    int unit = id >> 6, ln = id & 63;
    int li = ln & 15, g8 = (ln >> 4) * 8;
    float v[8];
    if (unit < 24) {                     // Wqkv [192][64]
      int rt = unit >> 1, ks2 = unit & 1;
      const float* s = &Wqkv[(rt * 16 + li) * 64 + ks2 * 32 + g8];
#pragma unroll
      for (int r = 0; r < 8; ++r) v[r] = s[r];
    } else if (unit < 56) {              // W1 [256][64]
      int u = unit - 24, rt = u >> 1, ks2 = u & 1;
      const float* s = &W1[(rt * 16 + li) * 64 + ks2 * 32 + g8];
#pragma unroll
      for (int r = 0; r < 8; ++r) v[r] = s[r];
    } else if (unit < 88) {              // W2 [64][256]
      int u = unit - 56, ct = u >> 3, ks2 = u & 7;
      const float* s = &W2[(ct * 16 + li) * 256 + ks2 * 32 + g8];
#pragma unroll
      for (int r = 0; r < 8; ++r) v[r] = s[r];
    } else {                             // conv_w [150][81] pad [160][96]
      int u = unit - 88, ct = u / 3, ks2 = u - ct * 3;
      int row = ct * 16 + li;
#pragma unroll
      for (int r = 0; r < 8; ++r) {
        int col = ks2 * 32 + g8 + r;
        v[r] = (row < 150 && col < 81) ? conv_w[row * 81 + col] : 0.f;
      }
    }
    half8 o;
#pragma unroll
    for (int r = 0; r < 8; ++r) o[r] = (half_t)v[r];
    ((half8*)dst)[id] = o;
  } else if (id < 11136) {
    int id2 = id - 7552;
    int unit = id2 >> 6, ln = id2 & 63;
    int li = ln & 15, gq = (ln >> 4) * 4;
    float v[4];
    if (unit < 16) {                     // Wo [64][64], K=16 frags
      int ct = unit >> 2, h = unit & 3;
      const float* s = &Wo[(ct * 16 + li) * 64 + h * 16 + gq];
#pragma unroll
      for (int r = 0; r < 4; ++r) v[r] = s[r];
    } else {                             // proj_w [64][150] pad [64][160]
      int u = unit - 16, dt = u / 10, ct = u - dt * 10;
#pragma unroll
      for (int r = 0; r < 4; ++r) {
        int col = ct * 16 + gq + r;
        v[r] = (col < 150) ? proj_w[(dt * 16 + li) * 150 + col] : 0.f;
      }
    }
    half4 o;
#pragma unroll
    for (int r = 0; r < 4; ++r) o[r] = (half_t)v[r];
    ((half4*)(dst + 60416))[id2] = o;
  }
}

// ---------------------------------------------------------------------------
// k_net v6 (R9 shape + VALU diet): conv -> LN1 -> attn (2 head-pair passes)
// -> LN2 -> FFN (4x64) -> tln. Residual in registers; 69,632B LDS.
// launch_bounds(512,4): min-waves=6 forces 40-VGPR spill tier (R8/R10) — avoid.
// VALU cuts vs R9: softmax denominator via ones-MFMA (es = column-sum on the
// matrix pipe, no serial add chain, no shuffles); packed f32->f16 cvts.
// LDS (bytes): Xh@0 (26,624; xsh 2,520 + OS 34,816 alias)
//   attn: Kb@26,624 (16,640 [2][208][20]) VT@43,264 (13,568 [2][16][212])
//   ffn:  W1S@26,624 (8,192) W2S@34,816 (8,192) Hb@43,008 (26,624)
// ---------------------------------------------------------------------------
__global__ __launch_bounds__(512, 4) void k_net(
    const float* __restrict__ x,
    const half8* __restrict__ WQ8, const half8* __restrict__ W18,
    const half8* __restrict__ W28, const half8* __restrict__ Wc8,
    const half4* __restrict__ WO4, const half4* __restrict__ Pw4,
    const float* __restrict__ proj_b,
    const float* __restrict__ ln1_g, const float* __restrict__ ln1_b,
    const float* __restrict__ bqkv, const float* __restrict__ bo,
    const float* __restrict__ ln2_g, const float* __restrict__ ln2_b,
    const float* __restrict__ b1, const float* __restrict__ b2,
    const float* __restrict__ tln_g, const float* __restrict__ tln_b,
    float* __restrict__ tokens) {
  extern __shared__ __align__(16) char pool[];
  half_t* xsh = (half_t*)pool;                 // conv phase alias
  half_t* Xh = (half_t*)pool;                  // LN1..FFN [208][64]
  half_t* Kb = (half_t*)(pool + 26624);        // attn: 2 heads [208][20]
  half_t* VT = (half_t*)(pool + 43264);        // attn: 2 heads [16][212]
  half8* W1S = (half8*)(pool + 26624);         // ffn alias, 8 units
  half8* W2S = (half8*)(pool + 34816);         // ffn alias, 8 units
  half_t* Hb = (half_t*)(pool + 43008);        // ffn alias [208][64]
  float* OS = (float*)pool;                    // out alias, 8x16x68 f32

  const int b = blockIdx.x, tid = threadIdx.x;
  const int wv = tid >> 6, ln = tid & 63, g = ln >> 4, li = ln & 15;
  const size_t base = (size_t)b * 12544;
  const half_t h1 = (half_t)1.f;
  const half4 ones = {h1, h1, h1, h1};

  f32x4 res[2][4];
#pragma unroll
  for (int qi = 0; qi < 2; ++qi)
#pragma unroll
    for (int ct = 0; ct < 4; ++ct) res[qi][ct] = f32x4{0.f, 0.f, 0.f, 0.f};

  // ---- conv phase: stage image as f16 ----
  for (int i = tid; i < 1260; i += 512) xsh[i] = (half_t)0.f;
  __syncthreads();
  for (int i = tid; i < 784; i += 512) {
    int r = i / 28, c = i - r * 28;
    xsh[(r + 4) * 36 + c + 4] = (half_t)x[b * 784 + i];
  }
  __syncthreads();

#pragma unroll
  for (int qi = 0; qi < 2; ++qi) {
    int qt = wv + 8 * qi;
    if (qt < 13) {
      int pp = qt * 16 + li;
      int pc = (pp < 196) ? pp : 195;
      int oy = pc / 14, ox = pc - oy * 14;
      int pbase = oy * 72 + ox * 2;
      half8 bf[3];
#pragma unroll
      for (int ks2 = 0; ks2 < 3; ++ks2) {
#pragma unroll
        for (int j = 0; j < 8; ++j) {
          int tap = ks2 * 32 + g * 8 + j;   // 0..95, valid <= 80
          half_t v = (half_t)0.f;
          if (tap <= 80) {
            int ky = tap / 9;
            v = xsh[pbase + ky * 27 + tap];
          }
          bf[ks2][j] = v;
        }
      }
      // ct-outer / dt-inner: only ONE hf fragment live
#pragma unroll
      for (int ct = 0; ct < 10; ++ct) {
        f32x4 acc = {0.f, 0.f, 0.f, 0.f};
#pragma unroll
        for (int ks2 = 0; ks2 < 3; ++ks2)
          acc = MFMA32(Wc8[(ct * 3 + ks2) * 64 + ln], bf[ks2], acc);
        half4 hf = PK4(fast_gelu(acc[0]), fast_gelu(acc[1]),
                       fast_gelu(acc[2]), fast_gelu(acc[3]));
#pragma unroll
        for (int dt = 0; dt < 4; ++dt)
          res[qi][dt] = MFMA16(Pw4[(dt * 10 + ct) * 64 + ln], hf, res[qi][dt]);
      }
#pragma unroll
      for (int dt = 0; dt < 4; ++dt) {
        float4 pb4 = *(const float4*)&proj_b[dt * 16 + g * 4];
        res[qi][dt][0] += pb4.x; res[qi][dt][1] += pb4.y;
        res[qi][dt][2] += pb4.z; res[qi][dt][3] += pb4.w;
      }
    }
  }
  __syncthreads();   // xsh done; Xh region free

  // ---- LN1 (in-register) -> Xh ----
  for (int i = tid; i < 768; i += 512)
    Xh[(196 + (i >> 6)) * 64 + (i & 63)] = (half_t)0.f;
#pragma unroll
  for (int qi = 0; qi < 2; ++qi) {
    int qt = wv + 8 * qi;
    if (qt < 13) {
      float sum = 0.f;
#pragma unroll
      for (int ct = 0; ct < 4; ++ct)
#pragma unroll
        for (int r = 0; r < 4; ++r) sum += res[qi][ct][r];
      sum += __shfl_xor(sum, 16, 64);
      sum += __shfl_xor(sum, 32, 64);
      float mu = sum * 0.015625f;
      float vs = 0.f;
#pragma unroll
      for (int ct = 0; ct < 4; ++ct)
#pragma unroll
        for (int r = 0; r < 4; ++r) { float d = res[qi][ct][r] - mu; vs += d * d; }
      vs += __shfl_xor(vs, 16, 64);
      vs += __shfl_xor(vs, 32, 64);
      float rs = rsqrtf(vs * 0.015625f + 1e-5f);
      int t = qt * 16 + li;
      if (t < 196) {
#pragma unroll
        for (int ct = 0; ct < 4; ++ct) {
          int k0 = ct * 16 + g * 4;
          float4 gg = *(const float4*)&ln1_g[k0];
          float4 bb = *(const float4*)&ln1_b[k0];
          *(half4*)&Xh[XH8W(t, k0)] =
              PK4((res[qi][ct][0] - mu) * rs * gg.x + bb.x,
                  (res[qi][ct][1] - mu) * rs * gg.y + bb.y,
                  (res[qi][ct][2] - mu) * rs * gg.z + bb.z,
                  (res[qi][ct][3] - mu) * rs * gg.w + bb.w);
        }
      }
    }
  }
  __syncthreads();

  // ---- Q fragments for all 4 heads (scale folds 1/4*log2e) ----
  half4 qf[2][4];
#pragma unroll
  for (int qi = 0; qi < 2; ++qi) {
    int qt = wv + 8 * qi;
    if (qt < 13) {
#pragma unroll
      for (int h = 0; h < 4; ++h) {
        f32x4 acc = {0.f, 0.f, 0.f, 0.f};
#pragma unroll
        for (int ks2 = 0; ks2 < 2; ++ks2)
          acc = MFMA32(WQ8[(h * 2 + ks2) * 64 + ln],
                       *(const half8*)&Xh[XH8R(qt * 16 + li, ks2 * 4 + g)], acc);
        const float SC = 0.36067376022224085f;
        qf[qi][h] = PK4((acc[0] + bqkv[h * 16 + g * 4 + 0]) * SC,
                        (acc[1] + bqkv[h * 16 + g * 4 + 1]) * SC,
                        (acc[2] + bqkv[h * 16 + g * 4 + 2]) * SC,
                        (acc[3] + bqkv[h * 16 + g * 4 + 3]) * SC);
      }
    }
  }

  // ---- attention: 2 head-pair passes ----
  for (int p = 0; p < 2; ++p) {
    {
      int rt4 = wv & 3, hh = rt4 & 1;
      bool isK = rt4 < 2;
      int rtg = (isK ? 4 : 8) + 2 * p + hh;
      half8 af[2];
#pragma unroll
      for (int ks2 = 0; ks2 < 2; ++ks2) af[ks2] = WQ8[(rtg * 2 + ks2) * 64 + ln];
      float bias[4];
      int brow = (isK ? 64 : 128) + (2 * p + hh) * 16 + g * 4;
#pragma unroll
      for (int r = 0; r < 4; ++r) bias[r] = bqkv[brow + r];
      int ta = (wv < 4) ? 0 : 7, tz = (wv < 4) ? 7 : 13;
      for (int tt = ta; tt < tz; ++tt) {
        int trow = tt * 16 + li;
        f32x4 acc = {0.f, 0.f, 0.f, 0.f};
#pragma unroll
        for (int ks2 = 0; ks2 < 2; ++ks2)
          acc = MFMA32(af[ks2], *(const half8*)&Xh[XH8R(trow, ks2 * 4 + g)], acc);
        if (isK) {
          *(half4*)&Kb[(hh * 208 + trow) * 20 + g * 4] =
              PK4(acc[0] + bias[0], acc[1] + bias[1],
                  acc[2] + bias[2], acc[3] + bias[3]);
        } else {
#pragma unroll
          for (int r = 0; r < 4; ++r)
            VT[(hh * 16 + g * 4 + r) * 212 + trow] = (half_t)(acc[r] + bias[r]);
        }
      }
    }
    __syncthreads();
    // streamed QK^T -> exp2 -> PV; denominator via ones-MFMA (matrix pipe)
#pragma unroll
    for (int qi = 0; qi < 2; ++qi) {
      int qt = wv + 8 * qi;
      if (qt < 13) {
#pragma unroll
        for (int hh = 0; hh < 2; ++hh) {
          int hglob = 2 * p + hh;
          f32x4 oa = {0.f, 0.f, 0.f, 0.f};
          f32x4 o1 = {0.f, 0.f, 0.f, 0.f};
#pragma unroll
          for (int nt = 0; nt < 13; ++nt) {
            f32x4 zz = {0.f, 0.f, 0.f, 0.f};
            f32x4 sv = MFMA16(*(const half4*)&Kb[(hh * 208 + nt * 16 + li) * 20 + g * 4],
                              qf[qi][hglob], zz);
            if (nt == 12 && g > 0) { sv[0] = -3e38f; sv[1] = -3e38f; sv[2] = -3e38f; sv[3] = -3e38f; }
            half4 pf = PK4(EXP2F(sv[0]), EXP2F(sv[1]), EXP2F(sv[2]), EXP2F(sv[3]));
            oa = MFMA16(*(const half4*)&VT[(hh * 16 + li) * 212 + nt * 16 + g * 4],
                        pf, oa);
            o1 = MFMA16(ones, pf, o1);   // es accumulation on matrix pipe
          }
          float inv = 1.0f / o1[0];      // every row of o1 = column sum
          half4 of = PK4(oa[0] * inv, oa[1] * inv, oa[2] * inv, oa[3] * inv);
#pragma unroll
          for (int ct = 0; ct < 4; ++ct)
            res[qi][ct] = MFMA16(WO4[(ct * 4 + hglob) * 64 + ln], of, res[qi][ct]);
        }
      }
    }
    __syncthreads();
  }
  // + bo
#pragma unroll
  for (int qi = 0; qi < 2; ++qi) {
    int qt = wv + 8 * qi;
    if (qt < 13) {
#pragma unroll
      for (int ct = 0; ct < 4; ++ct) {
        float4 bb = *(const float4*)&bo[ct * 16 + g * 4];
        res[qi][ct][0] += bb.x; res[qi][ct][1] += bb.y;
        res[qi][ct][2] += bb.z; res[qi][ct][3] += bb.w;
      }
    }
  }

  // ---- LN2 -> Xh ----
#pragma unroll
  for (int qi = 0; qi < 2; ++qi) {
    int qt = wv + 8 * qi;
    if (qt < 13) {
      float sum = 0.f;
#pragma unroll
      for (int ct = 0; ct < 4; ++ct)
#pragma unroll
        for (int r = 0; r < 4; ++r) sum += res[qi][ct][r];
      sum += __shfl_xor(sum, 16, 64);
      sum += __shfl_xor(sum, 32, 64);
      float mu = sum * 0.015625f;
      float vs = 0.f;
#pragma unroll
      for (int ct = 0; ct < 4; ++ct)
#pragma unroll
        for (int r = 0; r < 4; ++r) { float d = res[qi][ct][r] - mu; vs += d * d; }
      vs += __shfl_xor(vs, 16, 64);
      vs += __shfl_xor(vs, 32, 64);
      float rs = rsqrtf(vs * 0.015625f + 1e-5f);
      int t = qt * 16 + li;
      if (t < 196) {
#pragma unroll
        for (int ct = 0; ct < 4; ++ct) {
          int k0 = ct * 16 + g * 4;
          float4 gg = *(const float4*)&ln2_g[k0];
          float4 bb = *(const float4*)&ln2_b[k0];
          *(half4*)&Xh[XH8W(t, k0)] =
              PK4((res[qi][ct][0] - mu) * rs * gg.x + bb.x,
                  (res[qi][ct][1] - mu) * rs * gg.y + bb.y,
                  (res[qi][ct][2] - mu) * rs * gg.z + bb.z,
                  (res[qi][ct][3] - mu) * rs * gg.w + bb.w);
        }
      }
    }
  }
  __syncthreads();

  // ---- FFN: 4 chunks of 64 hidden ----
  for (int ch = 0; ch < 4; ++ch) {
    {
      int u = tid >> 6, l2 = tid & 63;
      int lnt = u >> 1, ks2 = u & 1;
      W1S[u * 64 + l2] = W18[((ch * 4 + lnt) * 2 + ks2) * 64 + l2];
      int ct = u >> 1, k2 = u & 1;
      W2S[u * 64 + l2] = W28[(ct * 8 + ch * 2 + k2) * 64 + l2];
    }
    __syncthreads();
    // H = gelu(t2 @ W1^T + b1) -> Hb [208][64]
#pragma unroll
    for (int j = 0; j < 7; ++j) {
      int u = wv + 8 * j;
      if (u < 52) {
        int mt = u >> 2, lnt = u & 3;
        f32x4 acc = {0.f, 0.f, 0.f, 0.f};
#pragma unroll
        for (int ks2 = 0; ks2 < 2; ++ks2)
          acc = MFMA32(*(const half8*)&Xh[XH8R(mt * 16 + li, ks2 * 4 + g)],
                       W1S[(lnt * 2 + ks2) * 64 + ln], acc);
        float bb = b1[ch * 64 + lnt * 16 + li];
#pragma unroll
        for (int r = 0; r < 4; ++r)
          Hb[XH8W(mt * 16 + g * 4 + r, lnt * 16 + li)] = (half_t)fast_gelu(acc[r] + bb);
      }
    }
    __syncthreads();
    // res += W2 @ H  (K=64 over the chunk: 2 x MFMA32 per ct)
#pragma unroll
    for (int qi = 0; qi < 2; ++qi) {
      int qt = wv + 8 * qi;
      if (qt < 13) {
#pragma unroll
        for (int ct = 0; ct < 4; ++ct)
#pragma unroll
          for (int k2 = 0; k2 < 2; ++k2)
            res[qi][ct] = MFMA32(W2S[(ct * 2 + k2) * 64 + ln],
                                 *(const half8*)&Hb[XH8R(qt * 16 + li, k2 * 4 + g)],
                                 res[qi][ct]);
      }
    }
    __syncthreads();
  }
  // + b2
#pragma unroll
  for (int qi = 0; qi < 2; ++qi) {
    int qt = wv + 8 * qi;
    if (qt < 13) {
#pragma unroll
      for (int ct = 0; ct < 4; ++ct) {
        float4 bb = *(const float4*)&b2[ct * 16 + g * 4];
        res[qi][ct][0] += bb.x; res[qi][ct][1] += bb.y;
        res[qi][ct][2] += bb.z; res[qi][ct][3] += bb.w;
      }
    }
  }

  // ---- final LN -> per-wave OS staging -> coalesced store (no barrier) ----
#pragma unroll
  for (int qi = 0; qi < 2; ++qi) {
    int qt = wv + 8 * qi;
    if (qt < 13) {
      float sum = 0.f;
#pragma unroll
      for (int ct = 0; ct < 4; ++ct)
#pragma unroll
        for (int r = 0; r < 4; ++r) sum += res[qi][ct][r];
      sum += __shfl_xor(sum, 16, 64);
      sum += __shfl_xor(sum, 32, 64);
      float mu = sum * 0.015625f;
      float vs = 0.f;
#pragma unroll
      for (int ct = 0; ct < 4; ++ct)
#pragma unroll
        for (int r = 0; r < 4; ++r) { float d = res[qi][ct][r] - mu; vs += d * d; }
      vs += __shfl_xor(vs, 16, 64);
      vs += __shfl_xor(vs, 32, 64);
      float rs = rsqrtf(vs * 0.015625f + 1e-5f);
#pragma unroll
      for (int ct = 0; ct < 4; ++ct) {
        float4 gg = *(const float4*)&tln_g[ct * 16 + g * 4];
        float4 bb = *(const float4*)&tln_b[ct * 16 + g * 4];
        float4 o;
        o.x = (res[qi][ct][0] - mu) * rs * gg.x + bb.x;
        o.y = (res[qi][ct][1] - mu) * rs * gg.y + bb.y;
        o.z = (res[qi][ct][2] - mu) * rs * gg.z + bb.z;
        o.w = (res[qi][ct][3] - mu) * rs * gg.w + bb.w;
        *(float4*)&OS[wv * 1088 + li * 68 + ct * 16 + g * 4] = o;
      }
#pragma unroll
      for (int rep = 0; rep < 4; ++rep) {
        int r4 = rep * 64 + ln;
        int row = r4 >> 4, q = r4 & 15;
        int pp = qt * 16 + row;
        if (pp < 196)
          *(float4*)&tokens[base + (size_t)pp * 64 + q * 4] =
              *(const float4*)&OS[wv * 1088 + row * 68 + q * 4];
      }
    }
  }
}

// ---------------------------------------------------------------------------
// slots: plain load (tln applied) + slot attention + spmask + classifier (f32)
// ---------------------------------------------------------------------------
__global__ __launch_bounds__(256) void k_slots(
    const float* __restrict__ tokens, const float* __restrict__ slot_q,
    const float* __restrict__ cls_w, const float* __restrict__ cls_b,
    const int* __restrict__ use_spmask_p, const int* __restrict__ grid_p,
    float* __restrict__ out) {
  __shared__ float TOK[12544];
  __shared__ float Abuf[12 * 196];
  __shared__ float SQS[12 * 64];
  __shared__ float INV[196];
  __shared__ float VV[64];
  __shared__ float Pv[12];
  __shared__ float M2[12];
  __shared__ float ISN[12];
  __shared__ float ZS[2];

  const int b = blockIdx.x, tid = threadIdx.x;
  const size_t base = (size_t)b * 12544;
  (void)grid_p;

  for (int i = tid; i < 12544; i += 256) {
    int t = i >> 6, c = i & 63;
    TOK[SWi(t, c)] = tokens[base + i];
  }
  __syncthreads();
  if (tid < 196) {
    float ss = 0.f;
#pragma unroll
    for (int q = 0; q < 16; ++q) {
      float4 v = *(const float4*)&TOK[SW4i(tid, q)];
      ss += v.x * v.x + v.y * v.y + v.z * v.z + v.w * v.w;
    }
    INV[tid] = 1.0f / fmaxf(sqrtf(ss), 1e-12f);
  }
  if (tid < 192) {
    int m = tid >> 4, l = tid & 15;
    float ss = 0.f;
#pragma unroll
    for (int c = l; c < 64; c += 16) {
      float v = slot_q[m * 64 + c];
      ss += v * v;
    }
#pragma unroll
    for (int mm = 8; mm; mm >>= 1) ss += __shfl_xor(ss, mm, 64);
    float invq = 1.0f / fmaxf(sqrtf(ss), 1e-12f);
#pragma unroll
    for (int c = l; c < 64; c += 16) SQS[m * 64 + c] = slot_q[m * 64 + c] * invq;
  }
  __syncthreads();
  for (int i = tid; i < 2352; i += 256) {
    int m = i / 196, n = i - m * 196;
    float d = 0.f;
#pragma unroll
    for (int q = 0; q < 16; ++q) {
      float4 tv = *(const float4*)&TOK[SW4i(n, q)];
      float4 sv = *(const float4*)&SQS[m * 64 + q * 4];
      d += tv.x * sv.x + tv.y * sv.y + tv.z * sv.z + tv.w * sv.w;
    }
    Abuf[i] = d * INV[n] * 0.125f;
  }
  __syncthreads();
  const int use_spmask = *use_spmask_p;
  if (tid < 192) {
    int m = tid >> 4, l = tid & 15;
    float* Am = Abuf + m * 196;
    float mx = -1e30f;
    for (int n = l; n < 196; n += 16) mx = fmaxf(mx, Am[n]);
#pragma unroll
    for (int mm = 8; mm; mm >>= 1) mx = fmaxf(mx, __shfl_xor(mx, mm, 64));
    float se = 0.f, mc0 = 0.f, mc1 = 0.f, mc2 = 0.f, mc3 = 0.f;
    for (int n = l; n < 196; n += 16) {
      float e = __expf(Am[n] - mx);
      Am[n] = e;
      se += e;
      int yy = n / 14, xx = n - yy * 14;
      int cell = ((yy >= 7) ? 2 : 0) + ((xx >= 7) ? 1 : 0);
      mc0 += (cell == 0) ? e : 0.f;
      mc1 += (cell == 1) ? e : 0.f;
      mc2 += (cell == 2) ? e : 0.f;
      mc3 += (cell == 3) ? e : 0.f;
    }
#pragma unroll
    for (int mm = 8; mm; mm >>= 1) {
      se += __shfl_xor(se, mm, 64);
      mc0 += __shfl_xor(mc0, mm, 64);
      mc1 += __shfl_xor(mc1, mm, 64);
      mc2 += __shfl_xor(mc2, mm, 64);
      mc3 += __shfl_xor(mc3, mm, 64);
    }
    float invse = 1.0f / se;
    if (use_spmask) {
      int g1 = 0; float bv1 = mc0;
      if (mc1 > bv1) { bv1 = mc1; g1 = 1; }
      if (mc2 > bv1) { bv1 = mc2; g1 = 2; }
      if (mc3 > bv1) { bv1 = mc3; g1 = 3; }
      int g2 = -1; float bv2 = -1e30f;
      if (g1 != 0 && mc0 > bv2) { bv2 = mc0; g2 = 0; }
      if (g1 != 1 && mc1 > bv2) { bv2 = mc1; g2 = 1; }
      if (g1 != 2 && mc2 > bv2) { bv2 = mc2; g2 = 2; }
      if (g1 != 3 && mc3 > bv2) { bv2 = mc3; g2 = 3; }
      float sacc = 0.f;
      for (int n = l; n < 196; n += 16) {
        float a = Am[n] * invse;
        Am[n] = a;
        int yy = n / 14, xx = n - yy * 14;
        int cell = ((yy >= 7) ? 2 : 0) + ((xx >= 7) ? 1 : 0);
        sacc += (cell == g1 || cell == g2) ? a : 0.f;
      }
#pragma unroll
      for (int mm = 8; mm; mm >>= 1) sacc += __shfl_xor(sacc, mm, 64);
      float invs = 1.0f / fmaxf(sacc, 1e-8f);
      float m2acc = 0.f;
      for (int n = l; n < 196; n += 16) {
        int yy = n / 14, xx = n - yy * 14;
        int cell = ((yy >= 7) ? 2 : 0) + ((xx >= 7) ? 1 : 0);
        float a = (cell == g1 || cell == g2) ? (Am[n] * invs) : 0.f;
        Am[n] = a;
        m2acc += a;
      }
#pragma unroll
      for (int mm = 8; mm; mm >>= 1) m2acc += __shfl_xor(m2acc, mm, 64);
      if (l == 0) M2[m] = m2acc;
    } else {
      for (int n = l; n < 196; n += 16) Am[n] *= invse;
      if (l == 0) M2[m] = mx + logf(se);
    }
  }
  __syncthreads();
  if (tid == 0) {
    float mean = 0.f;
    for (int m = 0; m < 12; ++m) mean += M2[m];
    mean *= (1.0f / 12.0f);
    float zmax = -1e30f;
    for (int m = 0; m < 12; ++m) {
      float z = (M2[m] - mean) * 2.0f;
      Pv[m] = z;
      zmax = fmaxf(zmax, z);
    }
    float seP = 0.f;
    for (int m = 0; m < 12; ++m) {
      float e = __expf(Pv[m] - zmax);
      Pv[m] = e;
      seP += e;
    }
    float invP = 1.0f / seP;
    float sump = 0.f;
    for (int m = 0; m < 12; ++m) {
      float p = Pv[m] * invP;
      Pv[m] = p;
      sump += p;
    }
    ZS[0] = sump;
  }
  __syncthreads();
  for (int i = tid; i < 768; i += 256) {
    int m = i >> 6, c = i & 63;
    float a2 = 0.f;
    const float* Am = Abuf + m * 196;
    for (int n = 0; n < 196; ++n) a2 += Am[n] * TOK[SWi(n, c)];
    SQS[m * 64 + c] = a2;
  }
  __syncthreads();
  if (tid < 192) {
    int m = tid >> 4, l = tid & 15;
    float ss = 0.f;
#pragma unroll
    for (int c = l; c < 64; c += 16) {
      float v = SQS[m * 64 + c];
      ss += v * v;
    }
#pragma unroll
    for (int mm = 8; mm; mm >>= 1) ss += __shfl_xor(ss, mm, 64);
    if (l == 0) ISN[m] = 1.0f / fmaxf(sqrtf(ss), 1e-12f);
  }
  __syncthreads();
  if (tid < 64) {
    float v = 0.f;
#pragma unroll
    for (int m = 0; m < 12; ++m) v += Pv[m] * ISN[m] * SQS[m * 64 + tid];
    VV[tid] = v;
  }
  __syncthreads();
  if (tid < 47) {
    float a2 = 0.f;
#pragma unroll
    for (int q = 0; q < 16; ++q) {
      float4 w = *(const float4*)&cls_w[tid * 64 + q * 4];
      float4 v = *(const float4*)&VV[q * 4];
      a2 += w.x * v.x + w.y * v.y + w.z * v.z + w.w * v.w;
    }
    out[(size_t)b * 47 + tid] = a2 + cls_b[tid] * ZS[0];
  }
}

// ---------------------------------------------------------------------------
extern "C" void kernel_launch(void* const* d_in, const int* in_sizes, int n_in,
                              void* d_out, int out_size, void* d_ws, size_t ws_size,
                              hipStream_t stream) {
  (void)n_in; (void)out_size; (void)ws_size;
  const float* x      = (const float*)d_in[0];
  const float* conv_w = (const float*)d_in[1];
  const float* proj_w = (const float*)d_in[2];
  const float* proj_b = (const float*)d_in[3];
  const float* ln1_g  = (const float*)d_in[4];
  const float* ln1_b  = (const float*)d_in[5];
  const float* Wqkv   = (const float*)d_in[6];
  const float* bqkv   = (const float*)d_in[7];
  const float* Wo     = (const float*)d_in[8];
  const float* bo     = (const float*)d_in[9];
  const float* ln2_g  = (const float*)d_in[10];
  const float* ln2_b  = (const float*)d_in[11];
  const float* W1     = (const float*)d_in[12];
  const float* b1     = (const float*)d_in[13];
  const float* W2     = (const float*)d_in[14];
  const float* b2     = (const float*)d_in[15];
  const float* tln_g  = (const float*)d_in[16];
  const float* tln_b  = (const float*)d_in[17];
  const float* slot_q = (const float*)d_in[18];
  const float* cls_w  = (const float*)d_in[19];
  const float* cls_b  = (const float*)d_in[20];
  const int* use_spm  = (const int*)d_in[21];
  const int* spgrid   = (const int*)d_in[22];

  const int B = in_sizes[0] / 784;
  half_t* wsh = (half_t*)d_ws;
  const half8* WQ8 = (const half8*)wsh;                 // 24 units
  const half8* W18 = (const half8*)(wsh + 12288);       // 32 units
  const half8* W28 = (const half8*)(wsh + 28672);       // 32 units
  const half8* Wc8 = (const half8*)(wsh + 45056);       // 30 units
  const half4* WO4 = (const half4*)(wsh + 60416);       // 16 units
  const half4* Pw4 = (const half4*)(wsh + 64512);       // 40 units
  float* tokens = (float*)((char*)d_ws + 163840);

  k_prepack<<<22, 512, 0, stream>>>(conv_w, proj_w, Wqkv, Wo, W1, W2, wsh);

  const int shnet = 69632;
  (void)hipFuncSetAttribute((const void*)k_net,
                            hipFuncAttributeMaxDynamicSharedMemorySize, shnet);
  k_net<<<B, 512, shnet, stream>>>(x, WQ8, W18, W28, Wc8, WO4, Pw4, proj_b,
                                   ln1_g, ln1_b, bqkv, bo, ln2_g, ln2_b,
                                   b1, b2, tln_g, tln_b, tokens);

  k_slots<<<B, 256, 0, stream>>>(tokens, slot_q, cls_w, cls_b, use_spm, spgrid,
                                 (float*)d_out);
}

// Round 14
// 364.420 us; speedup vs baseline: 1.8093x; 1.0971x over previous
//
#include <hip/hip_runtime.h>
#include <math.h>

typedef _Float16 half_t;
typedef __attribute__((ext_vector_type(2))) _Float16 half2t;
typedef __attribute__((ext_vector_type(4))) _Float16 half4;
typedef __attribute__((ext_vector_type(8))) _Float16 half8;
typedef __attribute__((ext_vector_type(4))) float f32x4;

__device__ __forceinline__ f32x4 MFMA16(half4 a, half4 b, f32x4 c) {
  return __builtin_amdgcn_mfma_f32_16x16x16f16(a, b, c, 0, 0, 0);
}
__device__ __forceinline__ f32x4 MFMA32(half8 a, half8 b, f32x4 c) {
  return __builtin_amdgcn_mfma_f32_16x16x32_f16(a, b, c, 0, 0, 0);
}

#if __has_builtin(__builtin_amdgcn_exp2f)
#define EXP2F(x) __builtin_amdgcn_exp2f(x)
#else
#define EXP2F(x) exp2f(x)
#endif

// packed f32x2 -> f16x2 (v_cvt_pkrtz_f16_f32); builtin returns __fp16x2 which
// is a distinct clang type from _Float16x2 — bit_cast (same bits, no codegen).
__device__ __forceinline__ half2t cvt_pk(float a, float b) {
#if __has_builtin(__builtin_amdgcn_cvt_pkrtz)
  return __builtin_bit_cast(half2t, __builtin_amdgcn_cvt_pkrtz(a, b));
#else
  half2t r; r[0] = (half_t)a; r[1] = (half_t)b; return r;
#endif
}
__device__ __forceinline__ half4 PK4(float a, float b, float c, float d) {
  half2t lo = cvt_pk(a, b), hi = cvt_pk(c, d);
  return __builtin_shufflevector(lo, hi, 0, 1, 2, 3);
}

// XOR swizzle for 64-float f32 rows (quad ^= row&15)
__device__ __forceinline__ int SWi(int row, int col) {
  return (row << 6) | (((((col >> 2) ^ row) & 15)) << 2) | (col & 3);
}
__device__ __forceinline__ int SW4i(int row, int q) {
  return (row << 6) | ((((q ^ row) & 15)) << 2);
}
// f16 rows of 64 cols, 16B units: unit8 ^= row&7
__device__ __forceinline__ int XH8W(int t, int k0) {
  return (t << 6) | ((((k0 >> 3) ^ t) & 7) << 3) | (k0 & 7);
}
__device__ __forceinline__ int XH8R(int t, int u8) {
  return (t << 6) | (((u8 ^ t) & 7) << 3);
}

// fast exact-gelu via Abramowitz-Stegun 7.1.26 erf (|err| <= 1.5e-7)
__device__ __forceinline__ float fast_gelu(float v) {
  float x = 0.70710678118654752f * v;
  float ax = fabsf(x);
  float t = 1.0f / fmaf(0.3275911f, ax, 1.0f);
  float poly = t * fmaf(t, fmaf(t, fmaf(t, fmaf(t, 1.061405429f, -1.453152027f),
                                        1.421413741f), -0.284496736f), 0.254829592f);
  float e = EXP2F(-1.4426950408889634f * ax * ax);
  float erfax = fmaf(-poly, e, 1.0f);
  float er = __builtin_copysignf(erfax, x);
  return 0.5f * v * (1.0f + er);
}

// ---------------------------------------------------------------------------
// prepack: weights -> f16 MFMA fragment order (unchanged).
// h8 units (1024B): lane ln holds row tile*16+(ln&15), k = ks2*32+(ln>>4)*8+j.
//   WQ8[0,24) W18[24,56) W28[56,88) Wc8[88,118)
// h4 units (512B) at half-offset 60416: WO4 16 units, Pw4 40 units.
// ---------------------------------------------------------------------------
__global__ void k_prepack(const float* __restrict__ conv_w,
                          const float* __restrict__ proj_w,
                          const float* __restrict__ Wqkv,
                          const float* __restrict__ Wo,
                          const float* __restrict__ W1,
                          const float* __restrict__ W2,
                          half_t* __restrict__ dst) {
  int id = blockIdx.x * 512 + threadIdx.x;
  if (id < 7552) {
    int unit = id >> 6, ln = id & 63;
    int li = ln & 15, g8 = (ln >> 4) * 8;
    float v[8];
    if (unit < 24) {                     // Wqkv [192][64]
      int rt = unit >> 1, ks2 = unit & 1;
      const float* s = &Wqkv[(rt * 16 + li) * 64 + ks2 * 32 + g8];
#pragma unroll
      for (int r = 0; r < 8; ++r) v[r] = s[r];
    } else if (unit < 56) {              // W1 [256][64]
      int u = unit - 24, rt = u >> 1, ks2 = u & 1;
      const float* s = &W1[(rt * 16 + li) * 64 + ks2 * 32 + g8];
#pragma unroll
      for (int r = 0; r < 8; ++r) v[r] = s[r];
    } else if (unit < 88) {              // W2 [64][256]
      int u = unit - 56, ct = u >> 3, ks2 = u & 7;
      const float* s = &W2[(ct * 16 + li) * 256 + ks2 * 32 + g8];
#pragma unroll
      for (int r = 0; r < 8; ++r) v[r] = s[r];
    } else {                             // conv_w [150][81] pad [160][96]
      int u = unit - 88, ct = u / 3, ks2 = u - ct * 3;
      int row = ct * 16 + li;
#pragma unroll
      for (int r = 0; r < 8; ++r) {
        int col = ks2 * 32 + g8 + r;
        v[r] = (row < 150 && col < 81) ? conv_w[row * 81 + col] : 0.f;
      }
    }
    half8 o;
#pragma unroll
    for (int r = 0; r < 8; ++r) o[r] = (half_t)v[r];
    ((half8*)dst)[id] = o;
  } else if (id < 11136) {
    int id2 = id - 7552;
    int unit = id2 >> 6, ln = id2 & 63;
    int li = ln & 15, gq = (ln >> 4) * 4;
    float v[4];
    if (unit < 16) {                     // Wo [64][64], K=16 frags
      int ct = unit >> 2, h = unit & 3;
      const float* s = &Wo[(ct * 16 + li) * 64 + h * 16 + gq];
#pragma unroll
      for (int r = 0; r < 4; ++r) v[r] = s[r];
    } else {                             // proj_w [64][150] pad [64][160]
      int u = unit - 16, dt = u / 10, ct = u - dt * 10;
#pragma unroll
      for (int r = 0; r < 4; ++r) {
        int col = ct * 16 + gq + r;
        v[r] = (col < 150) ? proj_w[(dt * 16 + li) * 150 + col] : 0.f;
      }
    }
    half4 o;
#pragma unroll
    for (int r = 0; r < 4; ++r) o[r] = (half_t)v[r];
    ((half4*)(dst + 60416))[id2] = o;
  }
}

// ---------------------------------------------------------------------------
// k_net v7: FULLY FUSED — conv -> LN1 -> attn -> LN2 -> FFN -> tln -> slot
// attention -> spmask -> classifier. Tokens never touch global memory.
// Residual in registers; 69,632B LDS; launch_bounds(512,4) (min-waves=6
// forces 40-VGPR spill tier per R8/R10 — avoid).
// LDS (bytes), transformer phases:
//   Xh@0 (26,624; xsh 2,520 aliases in conv)
//   attn: Kb@26,624 (16,640 [2][208][20]) VT@43,264 (13,568 [2][16][212])
//   ffn:  W1S@26,624 (8,192) W2S@34,816 (8,192) Hb@43,008 (26,624)
// slot phase (aliases everything):
//   TOK@0 (50,176 f32 [196][64] swz) Abuf@50,176 (9,408) SQS@59,584 (3,072)
//   INV@62,656 (784) VV@63,440 (256) Pv/M2/ISN/ZS@63,696..63,848
// ---------------------------------------------------------------------------
__global__ __launch_bounds__(512, 4) void k_net(
    const float* __restrict__ x,
    const half8* __restrict__ WQ8, const half8* __restrict__ W18,
    const half8* __restrict__ W28, const half8* __restrict__ Wc8,
    const half4* __restrict__ WO4, const half4* __restrict__ Pw4,
    const float* __restrict__ proj_b,
    const float* __restrict__ ln1_g, const float* __restrict__ ln1_b,
    const float* __restrict__ bqkv, const float* __restrict__ bo,
    const float* __restrict__ ln2_g, const float* __restrict__ ln2_b,
    const float* __restrict__ b1, const float* __restrict__ b2,
    const float* __restrict__ tln_g, const float* __restrict__ tln_b,
    const float* __restrict__ slot_q, const float* __restrict__ cls_w,
    const float* __restrict__ cls_b, const int* __restrict__ use_spmask_p,
    float* __restrict__ out) {
  extern __shared__ __align__(16) char pool[];
  half_t* xsh = (half_t*)pool;                 // conv phase alias
  half_t* Xh = (half_t*)pool;                  // LN1..FFN [208][64]
  half_t* Kb = (half_t*)(pool + 26624);        // attn: 2 heads [208][20]
  half_t* VT = (half_t*)(pool + 43264);        // attn: 2 heads [16][212]
  half8* W1S = (half8*)(pool + 26624);         // ffn alias, 8 units
  half8* W2S = (half8*)(pool + 34816);         // ffn alias, 8 units
  half_t* Hb = (half_t*)(pool + 43008);        // ffn alias [208][64]
  // slot-phase aliases
  float* TOK = (float*)pool;                   // [196][64] swizzled f32
  float* Abuf = (float*)(pool + 50176);        // 12*196
  float* SQS = (float*)(pool + 59584);         // 12*64
  float* INV = (float*)(pool + 62656);         // 196
  float* VV = (float*)(pool + 63440);          // 64
  float* Pv = (float*)(pool + 63696);          // 12
  float* M2 = (float*)(pool + 63744);          // 12
  float* ISN = (float*)(pool + 63792);         // 12
  float* ZS = (float*)(pool + 63840);          // 2

  const int b = blockIdx.x, tid = threadIdx.x;
  const int wv = tid >> 6, ln = tid & 63, g = ln >> 4, li = ln & 15;
  const half_t h1 = (half_t)1.f;
  const half4 ones = {h1, h1, h1, h1};

  f32x4 res[2][4];
#pragma unroll
  for (int qi = 0; qi < 2; ++qi)
#pragma unroll
    for (int ct = 0; ct < 4; ++ct) res[qi][ct] = f32x4{0.f, 0.f, 0.f, 0.f};

  // ---- conv phase: stage image as f16 ----
  for (int i = tid; i < 1260; i += 512) xsh[i] = (half_t)0.f;
  __syncthreads();
  for (int i = tid; i < 784; i += 512) {
    int r = i / 28, c = i - r * 28;
    xsh[(r + 4) * 36 + c + 4] = (half_t)x[b * 784 + i];
  }
  __syncthreads();

#pragma unroll
  for (int qi = 0; qi < 2; ++qi) {
    int qt = wv + 8 * qi;
    if (qt < 13) {
      int pp = qt * 16 + li;
      int pc = (pp < 196) ? pp : 195;
      int oy = pc / 14, ox = pc - oy * 14;
      int pbase = oy * 72 + ox * 2;
      half8 bf[3];
#pragma unroll
      for (int ks2 = 0; ks2 < 3; ++ks2) {
#pragma unroll
        for (int j = 0; j < 8; ++j) {
          int tap = ks2 * 32 + g * 8 + j;   // 0..95, valid <= 80
          half_t v = (half_t)0.f;
          if (tap <= 80) {
            int ky = tap / 9;
            v = xsh[pbase + ky * 27 + tap];
          }
          bf[ks2][j] = v;
        }
      }
      // ct-outer / dt-inner: only ONE hf fragment live
#pragma unroll
      for (int ct = 0; ct < 10; ++ct) {
        f32x4 acc = {0.f, 0.f, 0.f, 0.f};
#pragma unroll
        for (int ks2 = 0; ks2 < 3; ++ks2)
          acc = MFMA32(Wc8[(ct * 3 + ks2) * 64 + ln], bf[ks2], acc);
        half4 hf = PK4(fast_gelu(acc[0]), fast_gelu(acc[1]),
                       fast_gelu(acc[2]), fast_gelu(acc[3]));
#pragma unroll
        for (int dt = 0; dt < 4; ++dt)
          res[qi][dt] = MFMA16(Pw4[(dt * 10 + ct) * 64 + ln], hf, res[qi][dt]);
      }
#pragma unroll
      for (int dt = 0; dt < 4; ++dt) {
        float4 pb4 = *(const float4*)&proj_b[dt * 16 + g * 4];
        res[qi][dt][0] += pb4.x; res[qi][dt][1] += pb4.y;
        res[qi][dt][2] += pb4.z; res[qi][dt][3] += pb4.w;
      }
    }
  }
  __syncthreads();   // xsh done; Xh region free

  // ---- LN1 (in-register) -> Xh ----
  for (int i = tid; i < 768; i += 512)
    Xh[(196 + (i >> 6)) * 64 + (i & 63)] = (half_t)0.f;
#pragma unroll
  for (int qi = 0; qi < 2; ++qi) {
    int qt = wv + 8 * qi;
    if (qt < 13) {
      float sum = 0.f;
#pragma unroll
      for (int ct = 0; ct < 4; ++ct)
#pragma unroll
        for (int r = 0; r < 4; ++r) sum += res[qi][ct][r];
      sum += __shfl_xor(sum, 16, 64);
      sum += __shfl_xor(sum, 32, 64);
      float mu = sum * 0.015625f;
      float vs = 0.f;
#pragma unroll
      for (int ct = 0; ct < 4; ++ct)
#pragma unroll
        for (int r = 0; r < 4; ++r) { float d = res[qi][ct][r] - mu; vs += d * d; }
      vs += __shfl_xor(vs, 16, 64);
      vs += __shfl_xor(vs, 32, 64);
      float rs = rsqrtf(vs * 0.015625f + 1e-5f);
      int t = qt * 16 + li;
      if (t < 196) {
#pragma unroll
        for (int ct = 0; ct < 4; ++ct) {
          int k0 = ct * 16 + g * 4;
          float4 gg = *(const float4*)&ln1_g[k0];
          float4 bb = *(const float4*)&ln1_b[k0];
          *(half4*)&Xh[XH8W(t, k0)] =
              PK4((res[qi][ct][0] - mu) * rs * gg.x + bb.x,
                  (res[qi][ct][1] - mu) * rs * gg.y + bb.y,
                  (res[qi][ct][2] - mu) * rs * gg.z + bb.z,
                  (res[qi][ct][3] - mu) * rs * gg.w + bb.w);
        }
      }
    }
  }
  __syncthreads();

  // ---- Q fragments for all 4 heads (scale folds 1/4*log2e) ----
  half4 qf[2][4];
#pragma unroll
  for (int qi = 0; qi < 2; ++qi) {
    int qt = wv + 8 * qi;
    if (qt < 13) {
#pragma unroll
      for (int h = 0; h < 4; ++h) {
        f32x4 acc = {0.f, 0.f, 0.f, 0.f};
#pragma unroll
        for (int ks2 = 0; ks2 < 2; ++ks2)
          acc = MFMA32(WQ8[(h * 2 + ks2) * 64 + ln],
                       *(const half8*)&Xh[XH8R(qt * 16 + li, ks2 * 4 + g)], acc);
        const float SC = 0.36067376022224085f;
        qf[qi][h] = PK4((acc[0] + bqkv[h * 16 + g * 4 + 0]) * SC,
                        (acc[1] + bqkv[h * 16 + g * 4 + 1]) * SC,
                        (acc[2] + bqkv[h * 16 + g * 4 + 2]) * SC,
                        (acc[3] + bqkv[h * 16 + g * 4 + 3]) * SC);
      }
    }
  }

  // ---- attention: 2 head-pair passes ----
  for (int p = 0; p < 2; ++p) {
    {
      int rt4 = wv & 3, hh = rt4 & 1;
      bool isK = rt4 < 2;
      int rtg = (isK ? 4 : 8) + 2 * p + hh;
      half8 af[2];
#pragma unroll
      for (int ks2 = 0; ks2 < 2; ++ks2) af[ks2] = WQ8[(rtg * 2 + ks2) * 64 + ln];
      float bias[4];
      int brow = (isK ? 64 : 128) + (2 * p + hh) * 16 + g * 4;
#pragma unroll
      for (int r = 0; r < 4; ++r) bias[r] = bqkv[brow + r];
      int ta = (wv < 4) ? 0 : 7, tz = (wv < 4) ? 7 : 13;
      for (int tt = ta; tt < tz; ++tt) {
        int trow = tt * 16 + li;
        f32x4 acc = {0.f, 0.f, 0.f, 0.f};
#pragma unroll
        for (int ks2 = 0; ks2 < 2; ++ks2)
          acc = MFMA32(af[ks2], *(const half8*)&Xh[XH8R(trow, ks2 * 4 + g)], acc);
        if (isK) {
          *(half4*)&Kb[(hh * 208 + trow) * 20 + g * 4] =
              PK4(acc[0] + bias[0], acc[1] + bias[1],
                  acc[2] + bias[2], acc[3] + bias[3]);
        } else {
#pragma unroll
          for (int r = 0; r < 4; ++r)
            VT[(hh * 16 + g * 4 + r) * 212 + trow] = (half_t)(acc[r] + bias[r]);
        }
      }
    }
    __syncthreads();
    // streamed QK^T -> exp2 -> PV; denominator via ones-MFMA (matrix pipe)
#pragma unroll
    for (int qi = 0; qi < 2; ++qi) {
      int qt = wv + 8 * qi;
      if (qt < 13) {
#pragma unroll
        for (int hh = 0; hh < 2; ++hh) {
          int hglob = 2 * p + hh;
          f32x4 oa = {0.f, 0.f, 0.f, 0.f};
          f32x4 o1 = {0.f, 0.f, 0.f, 0.f};
#pragma unroll
          for (int nt = 0; nt < 13; ++nt) {
            f32x4 zz = {0.f, 0.f, 0.f, 0.f};
            f32x4 sv = MFMA16(*(const half4*)&Kb[(hh * 208 + nt * 16 + li) * 20 + g * 4],
                              qf[qi][hglob], zz);
            if (nt == 12 && g > 0) { sv[0] = -3e38f; sv[1] = -3e38f; sv[2] = -3e38f; sv[3] = -3e38f; }
            half4 pf = PK4(EXP2F(sv[0]), EXP2F(sv[1]), EXP2F(sv[2]), EXP2F(sv[3]));
            oa = MFMA16(*(const half4*)&VT[(hh * 16 + li) * 212 + nt * 16 + g * 4],
                        pf, oa);
            o1 = MFMA16(ones, pf, o1);   // es accumulation on matrix pipe
          }
          float inv = 1.0f / o1[0];      // every row of o1 = column sum
          half4 of = PK4(oa[0] * inv, oa[1] * inv, oa[2] * inv, oa[3] * inv);
#pragma unroll
          for (int ct = 0; ct < 4; ++ct)
            res[qi][ct] = MFMA16(WO4[(ct * 4 + hglob) * 64 + ln], of, res[qi][ct]);
        }
      }
    }
    __syncthreads();
  }
  // + bo
#pragma unroll
  for (int qi = 0; qi < 2; ++qi) {
    int qt = wv + 8 * qi;
    if (qt < 13) {
#pragma unroll
      for (int ct = 0; ct < 4; ++ct) {
        float4 bb = *(const float4*)&bo[ct * 16 + g * 4];
        res[qi][ct][0] += bb.x; res[qi][ct][1] += bb.y;
        res[qi][ct][2] += bb.z; res[qi][ct][3] += bb.w;
      }
    }
  }

  // ---- LN2 -> Xh ----
#pragma unroll
  for (int qi = 0; qi < 2; ++qi) {
    int qt = wv + 8 * qi;
    if (qt < 13) {
      float sum = 0.f;
#pragma unroll
      for (int ct = 0; ct < 4; ++ct)
#pragma unroll
        for (int r = 0; r < 4; ++r) sum += res[qi][ct][r];
      sum += __shfl_xor(sum, 16, 64);
      sum += __shfl_xor(sum, 32, 64);
      float mu = sum * 0.015625f;
      float vs = 0.f;
#pragma unroll
      for (int ct = 0; ct < 4; ++ct)
#pragma unroll
        for (int r = 0; r < 4; ++r) { float d = res[qi][ct][r] - mu; vs += d * d; }
      vs += __shfl_xor(vs, 16, 64);
      vs += __shfl_xor(vs, 32, 64);
      float rs = rsqrtf(vs * 0.015625f + 1e-5f);
      int t = qt * 16 + li;
      if (t < 196) {
#pragma unroll
        for (int ct = 0; ct < 4; ++ct) {
          int k0 = ct * 16 + g * 4;
          float4 gg = *(const float4*)&ln2_g[k0];
          float4 bb = *(const float4*)&ln2_b[k0];
          *(half4*)&Xh[XH8W(t, k0)] =
              PK4((res[qi][ct][0] - mu) * rs * gg.x + bb.x,
                  (res[qi][ct][1] - mu) * rs * gg.y + bb.y,
                  (res[qi][ct][2] - mu) * rs * gg.z + bb.z,
                  (res[qi][ct][3] - mu) * rs * gg.w + bb.w);
        }
      }
    }
  }
  __syncthreads();

  // ---- FFN: 4 chunks of 64 hidden ----
  for (int ch = 0; ch < 4; ++ch) {
    {
      int u = tid >> 6, l2 = tid & 63;
      int lnt = u >> 1, ks2 = u & 1;
      W1S[u * 64 + l2] = W18[((ch * 4 + lnt) * 2 + ks2) * 64 + l2];
      int ct = u >> 1, k2 = u & 1;
      W2S[u * 64 + l2] = W28[(ct * 8 + ch * 2 + k2) * 64 + l2];
    }
    __syncthreads();
    // H = gelu(t2 @ W1^T + b1) -> Hb [208][64]
#pragma unroll
    for (int j = 0; j < 7; ++j) {
      int u = wv + 8 * j;
      if (u < 52) {
        int mt = u >> 2, lnt = u & 3;
        f32x4 acc = {0.f, 0.f, 0.f, 0.f};
#pragma unroll
        for (int ks2 = 0; ks2 < 2; ++ks2)
          acc = MFMA32(*(const half8*)&Xh[XH8R(mt * 16 + li, ks2 * 4 + g)],
                       W1S[(lnt * 2 + ks2) * 64 + ln], acc);
        float bb = b1[ch * 64 + lnt * 16 + li];
#pragma unroll
        for (int r = 0; r < 4; ++r)
          Hb[XH8W(mt * 16 + g * 4 + r, lnt * 16 + li)] = (half_t)fast_gelu(acc[r] + bb);
      }
    }
    __syncthreads();
    // res += W2 @ H  (K=64 over the chunk: 2 x MFMA32 per ct)
#pragma unroll
    for (int qi = 0; qi < 2; ++qi) {
      int qt = wv + 8 * qi;
      if (qt < 13) {
#pragma unroll
        for (int ct = 0; ct < 4; ++ct)
#pragma unroll
          for (int k2 = 0; k2 < 2; ++k2)
            res[qi][ct] = MFMA32(W2S[(ct * 2 + k2) * 64 + ln],
                                 *(const half8*)&Hb[XH8R(qt * 16 + li, k2 * 4 + g)],
                                 res[qi][ct]);
      }
    }
    __syncthreads();
  }
  // + b2
#pragma unroll
  for (int qi = 0; qi < 2; ++qi) {
    int qt = wv + 8 * qi;
    if (qt < 13) {
#pragma unroll
      for (int ct = 0; ct < 4; ++ct) {
        float4 bb = *(const float4*)&b2[ct * 16 + g * 4];
        res[qi][ct][0] += bb.x; res[qi][ct][1] += bb.y;
        res[qi][ct][2] += bb.z; res[qi][ct][3] += bb.w;
      }
    }
  }

  // ---- final LN (tln) -> TOK in LDS (f32 swizzled; no global store) ----
#pragma unroll
  for (int qi = 0; qi < 2; ++qi) {
    int qt = wv + 8 * qi;
    if (qt < 13) {
      float sum = 0.f;
#pragma unroll
      for (int ct = 0; ct < 4; ++ct)
#pragma unroll
        for (int r = 0; r < 4; ++r) sum += res[qi][ct][r];
      sum += __shfl_xor(sum, 16, 64);
      sum += __shfl_xor(sum, 32, 64);
      float mu = sum * 0.015625f;
      float vs = 0.f;
#pragma unroll
      for (int ct = 0; ct < 4; ++ct)
#pragma unroll
        for (int r = 0; r < 4; ++r) { float d = res[qi][ct][r] - mu; vs += d * d; }
      vs += __shfl_xor(vs, 16, 64);
      vs += __shfl_xor(vs, 32, 64);
      float rs = rsqrtf(vs * 0.015625f + 1e-5f);
      int t = qt * 16 + li;
      if (t < 196) {
#pragma unroll
        for (int ct = 0; ct < 4; ++ct) {
          int k0 = ct * 16 + g * 4;
          float4 gg = *(const float4*)&tln_g[k0];
          float4 bb = *(const float4*)&tln_b[k0];
          float4 o;
          o.x = (res[qi][ct][0] - mu) * rs * gg.x + bb.x;
          o.y = (res[qi][ct][1] - mu) * rs * gg.y + bb.y;
          o.z = (res[qi][ct][2] - mu) * rs * gg.z + bb.z;
          o.w = (res[qi][ct][3] - mu) * rs * gg.w + bb.w;
          *(float4*)&TOK[SWi(t, k0)] = o;   // k0 4-aligned: contiguous quad
        }
      }
    }
  }
  __syncthreads();

  // ======================= slot phase (fused k_slots) ======================
  if (tid < 196) {
    float ss = 0.f;
#pragma unroll
    for (int q = 0; q < 16; ++q) {
      float4 v = *(const float4*)&TOK[SW4i(tid, q)];
      ss += v.x * v.x + v.y * v.y + v.z * v.z + v.w * v.w;
    }
    INV[tid] = 1.0f / fmaxf(sqrtf(ss), 1e-12f);
  }
  if (tid < 192) {
    int m = tid >> 4, l = tid & 15;
    float ss = 0.f;
#pragma unroll
    for (int c = l; c < 64; c += 16) {
      float v = slot_q[m * 64 + c];
      ss += v * v;
    }
#pragma unroll
    for (int mm = 8; mm; mm >>= 1) ss += __shfl_xor(ss, mm, 64);
    float invq = 1.0f / fmaxf(sqrtf(ss), 1e-12f);
#pragma unroll
    for (int c = l; c < 64; c += 16) SQS[m * 64 + c] = slot_q[m * 64 + c] * invq;
  }
  __syncthreads();
  for (int i = tid; i < 2352; i += 512) {
    int m = i / 196, n = i - m * 196;
    float d = 0.f;
#pragma unroll
    for (int q = 0; q < 16; ++q) {
      float4 tv = *(const float4*)&TOK[SW4i(n, q)];
      float4 sv = *(const float4*)&SQS[m * 64 + q * 4];
      d += tv.x * sv.x + tv.y * sv.y + tv.z * sv.z + tv.w * sv.w;
    }
    Abuf[i] = d * INV[n] * 0.125f;
  }
  __syncthreads();
  const int use_spmask = *use_spmask_p;
  if (tid < 192) {
    int m = tid >> 4, l = tid & 15;
    float* Am = Abuf + m * 196;
    float mx = -1e30f;
    for (int n = l; n < 196; n += 16) mx = fmaxf(mx, Am[n]);
#pragma unroll
    for (int mm = 8; mm; mm >>= 1) mx = fmaxf(mx, __shfl_xor(mx, mm, 64));
    float se = 0.f, mc0 = 0.f, mc1 = 0.f, mc2 = 0.f, mc3 = 0.f;
    for (int n = l; n < 196; n += 16) {
      float e = __expf(Am[n] - mx);
      Am[n] = e;
      se += e;
      int yy = n / 14, xx = n - yy * 14;
      int cell = ((yy >= 7) ? 2 : 0) + ((xx >= 7) ? 1 : 0);
      mc0 += (cell == 0) ? e : 0.f;
      mc1 += (cell == 1) ? e : 0.f;
      mc2 += (cell == 2) ? e : 0.f;
      mc3 += (cell == 3) ? e : 0.f;
    }
#pragma unroll
    for (int mm = 8; mm; mm >>= 1) {
      se += __shfl_xor(se, mm, 64);
      mc0 += __shfl_xor(mc0, mm, 64);
      mc1 += __shfl_xor(mc1, mm, 64);
      mc2 += __shfl_xor(mc2, mm, 64);
      mc3 += __shfl_xor(mc3, mm, 64);
    }
    float invse = 1.0f / se;
    if (use_spmask) {
      int g1 = 0; float bv1 = mc0;
      if (mc1 > bv1) { bv1 = mc1; g1 = 1; }
      if (mc2 > bv1) { bv1 = mc2; g1 = 2; }
      if (mc3 > bv1) { bv1 = mc3; g1 = 3; }
      int g2 = -1; float bv2 = -1e30f;
      if (g1 != 0 && mc0 > bv2) { bv2 = mc0; g2 = 0; }
      if (g1 != 1 && mc1 > bv2) { bv2 = mc1; g2 = 1; }
      if (g1 != 2 && mc2 > bv2) { bv2 = mc2; g2 = 2; }
      if (g1 != 3 && mc3 > bv2) { bv2 = mc3; g2 = 3; }
      float sacc = 0.f;
      for (int n = l; n < 196; n += 16) {
        float a = Am[n] * invse;
        Am[n] = a;
        int yy = n / 14, xx = n - yy * 14;
        int cell = ((yy >= 7) ? 2 : 0) + ((xx >= 7) ? 1 : 0);
        sacc += (cell == g1 || cell == g2) ? a : 0.f;
      }
#pragma unroll
      for (int mm = 8; mm; mm >>= 1) sacc += __shfl_xor(sacc, mm, 64);
      float invs = 1.0f / fmaxf(sacc, 1e-8f);
      float m2acc = 0.f;
      for (int n = l; n < 196; n += 16) {
        int yy = n / 14, xx = n - yy * 14;
        int cell = ((yy >= 7) ? 2 : 0) + ((xx >= 7) ? 1 : 0);
        float a = (cell == g1 || cell == g2) ? (Am[n] * invs) : 0.f;
        Am[n] = a;
        m2acc += a;
      }
#pragma unroll
      for (int mm = 8; mm; mm >>= 1) m2acc += __shfl_xor(m2acc, mm, 64);
      if (l == 0) M2[m] = m2acc;
    } else {
      for (int n = l; n < 196; n += 16) Am[n] *= invse;
      if (l == 0) M2[m] = mx + logf(se);
    }
  }
  __syncthreads();
  if (tid == 0) {
    float mean = 0.f;
    for (int m = 0; m < 12; ++m) mean += M2[m];
    mean *= (1.0f / 12.0f);
    float zmax = -1e30f;
    for (int m = 0; m < 12; ++m) {
      float z = (M2[m] - mean) * 2.0f;
      Pv[m] = z;
      zmax = fmaxf(zmax, z);
    }
    float seP = 0.f;
    for (int m = 0; m < 12; ++m) {
      float e = __expf(Pv[m] - zmax);
      Pv[m] = e;
      seP += e;
    }
    float invP = 1.0f / seP;
    float sump = 0.f;
    for (int m = 0; m < 12; ++m) {
      float p = Pv[m] * invP;
      Pv[m] = p;
      sump += p;
    }
    ZS[0] = sump;
  }
  __syncthreads();
  // S[m][c] = sum_n A_eff[m][n] * TOK[n][c]
  for (int i = tid; i < 768; i += 512) {
    int m = i >> 6, c = i & 63;
    float a2 = 0.f;
    const float* Am = Abuf + m * 196;
    for (int n = 0; n < 196; ++n) a2 += Am[n] * TOK[SWi(n, c)];
    SQS[m * 64 + c] = a2;
  }
  __syncthreads();
  if (tid < 192) {
    int m = tid >> 4, l = tid & 15;
    float ss = 0.f;
#pragma unroll
    for (int c = l; c < 64; c += 16) {
      float v = SQS[m * 64 + c];
      ss += v * v;
    }
#pragma unroll
    for (int mm = 8; mm; mm >>= 1) ss += __shfl_xor(ss, mm, 64);
    if (l == 0) ISN[m] = 1.0f / fmaxf(sqrtf(ss), 1e-12f);
  }
  __syncthreads();
  if (tid < 64) {
    float v = 0.f;
#pragma unroll
    for (int m = 0; m < 12; ++m) v += Pv[m] * ISN[m] * SQS[m * 64 + tid];
    VV[tid] = v;
  }
  __syncthreads();
  if (tid < 47) {
    float a2 = 0.f;
#pragma unroll
    for (int q = 0; q < 16; ++q) {
      float4 w = *(const float4*)&cls_w[tid * 64 + q * 4];
      float4 v = *(const float4*)&VV[q * 4];
      a2 += w.x * v.x + w.y * v.y + w.z * v.z + w.w * v.w;
    }
    out[(size_t)b * 47 + tid] = a2 + cls_b[tid] * ZS[0];
  }
}

// ---------------------------------------------------------------------------
extern "C" void kernel_launch(void* const* d_in, const int* in_sizes, int n_in,
                              void* d_out, int out_size, void* d_ws, size_t ws_size,
                              hipStream_t stream) {
  (void)n_in; (void)out_size; (void)ws_size;
  const float* x      = (const float*)d_in[0];
  const float* conv_w = (const float*)d_in[1];
  const float* proj_w = (const float*)d_in[2];
  const float* proj_b = (const float*)d_in[3];
  const float* ln1_g  = (const float*)d_in[4];
  const float* ln1_b  = (const float*)d_in[5];
  const float* Wqkv   = (const float*)d_in[6];
  const float* bqkv   = (const float*)d_in[7];
  const float* Wo     = (const float*)d_in[8];
  const float* bo     = (const float*)d_in[9];
  const float* ln2_g  = (const float*)d_in[10];
  const float* ln2_b  = (const float*)d_in[11];
  const float* W1     = (const float*)d_in[12];
  const float* b1     = (const float*)d_in[13];
  const float* W2     = (const float*)d_in[14];
  const float* b2     = (const float*)d_in[15];
  const float* tln_g  = (const float*)d_in[16];
  const float* tln_b  = (const float*)d_in[17];
  const float* slot_q = (const float*)d_in[18];
  const float* cls_w  = (const float*)d_in[19];
  const float* cls_b  = (const float*)d_in[20];
  const int* use_spm  = (const int*)d_in[21];

  const int B = in_sizes[0] / 784;
  half_t* wsh = (half_t*)d_ws;
  const half8* WQ8 = (const half8*)wsh;                 // 24 units
  const half8* W18 = (const half8*)(wsh + 12288);       // 32 units
  const half8* W28 = (const half8*)(wsh + 28672);       // 32 units
  const half8* Wc8 = (const half8*)(wsh + 45056);       // 30 units
  const half4* WO4 = (const half4*)(wsh + 60416);       // 16 units
  const half4* Pw4 = (const half4*)(wsh + 64512);       // 40 units

  k_prepack<<<22, 512, 0, stream>>>(conv_w, proj_w, Wqkv, Wo, W1, W2, wsh);

  const int shnet = 69632;
  (void)hipFuncSetAttribute((const void*)k_net,
                            hipFuncAttributeMaxDynamicSharedMemorySize, shnet);
  k_net<<<B, 512, shnet, stream>>>(x, WQ8, W18, W28, Wc8, WO4, Pw4, proj_b,
                                   ln1_g, ln1_b, bqkv, bo, ln2_g, ln2_b,
                                   b1, b2, tln_g, tln_b, slot_q, cls_w, cls_b,
                                   use_spm, (float*)d_out);
}